// Round 1
// baseline (36710.809 us; speedup 1.0000x reference)
//
#include <hip/hip_runtime.h>

typedef unsigned int uint;
typedef unsigned short ushort;
typedef __attribute__((ext_vector_type(8))) short bf16x8;
typedef __attribute__((ext_vector_type(4))) float f32x4;

static constexpr int V_ = 32000, E_ = 256, H_ = 512, B_ = 16, S_ = 512, T_ = 128;
static constexpr int H2_ = 1024, G4_ = 2048, D4_ = 4096, KXI_ = 2304; // 256+1024+1024
static constexpr int DSTEPS = T_ - 1;  // 127
static constexpr int MD = 2048;        // padded rows for preds GEMM (2032 valid)

#define DEVFN __device__ __forceinline__

DEVFN ushort f2bf(float f){ uint u = __builtin_bit_cast(uint, f); u += 0x7fffu + ((u>>16)&1u); return (ushort)(u>>16); }
DEVFN float bf2f(ushort h){ uint u = ((uint)h)<<16; return __builtin_bit_cast(float, u); }
DEVFN float fsig(float x){ float e = __builtin_amdgcn_exp2f(-1.4426950408889634f*x); return __builtin_amdgcn_rcpf(1.f+e); }
DEVFN float ftanh(float x){ x = fminf(15.f,fmaxf(-15.f,x)); float e = __builtin_amdgcn_exp2f(2.8853900817779268f*x); return (e-1.f)*__builtin_amdgcn_rcpf(e+1.f); }
DEVFN f32x4 mfma16(bf16x8 a, bf16x8 b, f32x4 c){ return __builtin_amdgcn_mfma_f32_16x16x32_bf16(a,b,c,0,0,0); }

// ---------------- embedding gather (src -> Xb bf16, tgt -> DXb bf16) ----------------
__global__ void k_embed(const int* __restrict__ src, const int* __restrict__ tgt,
                        const float* __restrict__ emb, ushort* __restrict__ Xb, ushort* __restrict__ DXb){
  int r = blockIdx.x, tid = threadIdx.x;
  if (r < S_*B_){
    int s = r>>4, b = r&15;
    int id = src[b*S_+s];
    Xb[(size_t)r*E_+tid] = f2bf(emb[(size_t)id*E_+tid]);
  } else {
    int r2 = r - S_*B_;
    int t = r2>>4, b = r2&15;
    int id = tgt[b*T_+t];
    DXb[(size_t)r2*E_+tid] = f2bf(emb[(size_t)id*E_+tid]);
  }
}

// encoder weight convert with gate-row permutation: dst row d = w*256+g*64+jj <- src row g*512+w*64+jj
__global__ void k_cvt_encw(const float* __restrict__ src, ushort* __restrict__ dst, int Kc){
  int d = blockIdx.x;
  int w = d>>8, g = (d>>6)&3, jj = d&63;
  int srow = g*H_ + w*64 + jj;
  for (int c = threadIdx.x; c < Kc; c += 256)
    dst[(size_t)d*Kc + c] = f2bf(src[(size_t)srow*Kc + c]);
}

__global__ void k_bias_encp(const float* __restrict__ bih, const float* __restrict__ bhh, float* __restrict__ dst){
  int d = blockIdx.x*256 + threadIdx.x;
  int w = d>>8, g=(d>>6)&3, jj=d&63;
  int srow = g*H_ + w*64 + jj;
  dst[d] = bih[srow]+bhh[srow];
}

__global__ void k_cvt_strided(const float* __restrict__ src, ushort* __restrict__ dst,
                              int cols, int sld, int soff, int dld, int doff){
  int r = blockIdx.x;
  for (int c = threadIdx.x; c < cols; c += 256)
    dst[(size_t)r*dld + doff + c] = f2bf(src[(size_t)r*sld + soff + c]);
}

__global__ void k_addb(const float* __restrict__ a, const float* __restrict__ b, float* __restrict__ o, int n){
  int i = blockIdx.x*256+threadIdx.x; if (i<n) o[i]=a[i]+b[i];
}

__global__ void k_zero_t0(float* __restrict__ out){
  int i = blockIdx.x*256 + threadIdx.x;
  if (i < B_*V_){ int b = i / V_, v = i - b*V_; out[(size_t)b*T_*V_ + v] = 0.f; }
}

// ---------------- 128x128-tile bf16 MFMA GEMM: C[M,N] = A[MxK] @ B[NxK]^T + bias ----------------
// MODE 0: f32 out (ld=N). MODE 1: bf16 out (ld=N). MODE 2: scatter preds to out[b,t+1,v], guard row<Mvalid.
template<int MODE>
__global__ __launch_bounds__(256) void gemm128(const ushort* __restrict__ A, const ushort* __restrict__ Bm,
    const float* __restrict__ bias, void* __restrict__ outp, int M, int N, int K, int Mvalid){
  __shared__ __align__(16) ushort As[128*32];
  __shared__ __align__(16) ushort Bs[128*32];
  int tid = threadIdx.x;
  int wave = tid>>6, lane = tid&63;
  int m0 = blockIdx.y*128, n0 = blockIdx.x*128;
  int wm = wave>>1, wn = wave&1;
  int col = lane&15, rg = lane>>4;
  f32x4 acc[4][4];
  #pragma unroll
  for (int i=0;i<4;i++)
    #pragma unroll
    for (int j=0;j<4;j++) acc[i][j] = {0.f,0.f,0.f,0.f};
  for (int k0=0;k0<K;k0+=32){
    __syncthreads();
    #pragma unroll
    for (int j=0;j<2;j++){
      int li = j*256+tid;
      int row = li>>2, ko = (li&3)*8;
      *(bf16x8*)(As + li*8) = *(const bf16x8*)(A + (size_t)(m0+row)*K + k0 + ko);
      *(bf16x8*)(Bs + li*8) = *(const bf16x8*)(Bm + (size_t)(n0+row)*K + k0 + ko);
    }
    __syncthreads();
    bf16x8 af[4], bfr[4];
    #pragma unroll
    for (int f=0;f<4;f++){
      af[f]  = *(const bf16x8*)(As + (wm*64+f*16+col)*32 + rg*8);
      bfr[f] = *(const bf16x8*)(Bs + (wn*64+f*16+col)*32 + rg*8);
    }
    #pragma unroll
    for (int fm=0;fm<4;fm++)
      #pragma unroll
      for (int fn=0;fn<4;fn++)
        acc[fm][fn] = mfma16(af[fm], bfr[fn], acc[fm][fn]);
  }
  #pragma unroll
  for (int fm=0;fm<4;fm++){
    int mrow = m0 + wm*64 + fm*16 + rg*4;
    #pragma unroll
    for (int fn=0;fn<4;fn++){
      int gcol = n0 + wn*64 + fn*16 + col;
      float bv = bias ? bias[gcol] : 0.f;
      #pragma unroll
      for (int i=0;i<4;i++){
        float v = acc[fm][fn][i] + bv;
        int grow = mrow + i;
        if (MODE==0) ((float*)outp)[(size_t)grow*N + gcol] = v;
        else if (MODE==1) ((ushort*)outp)[(size_t)grow*N + gcol] = f2bf(v);
        else { if (grow < Mvalid){ int b = grow&15, t = grow>>4;
               ((float*)outp)[(size_t)b*T_*V_ + (size_t)(t+1)*V_ + gcol] = v; } }
      }
    }
  }
}

// ---------------- small-M (M=16) MFMA GEMM: out[16,N] = A[16xK](lda) @ B[NxK]^T + bias ----------------
__global__ __launch_bounds__(128) void k_smallm(const ushort* __restrict__ A, int lda,
    const ushort* __restrict__ Bm, const float* __restrict__ bias,
    float* __restrict__ out, int ldo, int N, int K){
  int wv = blockIdx.x*2 + (threadIdx.x>>6);
  int n0 = wv*16;
  if (n0 >= N) return;
  int lane = threadIdx.x&63, col = lane&15, rg = lane>>4;
  float bv = bias ? bias[n0+col] : 0.f;
  f32x4 acc = {bv,bv,bv,bv};
  const ushort* Ap = A + (size_t)col*lda + rg*8;
  const ushort* Bp = Bm + (size_t)(n0+col)*K + rg*8;
  for (int k=0;k<K;k+=32){
    bf16x8 a = *(const bf16x8*)(Ap + k);
    bf16x8 b = *(const bf16x8*)(Bp + k);
    acc = mfma16(a,b,acc);
  }
  #pragma unroll
  for (int i=0;i<4;i++)
    out[(size_t)(rg*4+i)*ldo + n0 + col] = acc[i];
}

// ---------------- persistent encoder: 1 WG per direction, 8 waves, MFMA, 1 barrier/step ----------------
__global__ __launch_bounds__(512) void k_encoder(const ushort* __restrict__ Xgf, const ushort* __restrict__ Xgb,
    const ushort* __restrict__ Whhf, const ushort* __restrict__ Whhb,
    ushort* __restrict__ enc, ushort* __restrict__ xi, float* __restrict__ cbuf){
  const int dir = blockIdx.x;
  const ushort* Xg  = dir ? Xgb : Xgf;
  const ushort* Whh = dir ? Whhb : Whhf;
  __shared__ __align__(16) ushort hls[2*16*512];  // [buf][b][k] bf16, XOR-swizzled
  int tid = threadIdx.x;
  for (int i=tid;i<2*16*512;i+=512) hls[i] = 0;
  int w = tid>>6, lane = tid&63, col = lane&15, rg = lane>>4;
  float cst[16];
  #pragma unroll
  for (int i=0;i<16;i++) cst[i]=0.f;
  const int albase = col*1024 + rg*16;        // A-frag linear byte base (b=col)
  const int axmask = (col&7)<<4;              // T2 XOR swizzle
  __syncthreads();
  int cur = 0;
  for (int t=0;t<S_;++t){
    int pos = dir ? (S_-1-t) : t;
    f32x4 acc[4][4];
    #pragma unroll
    for (int g=0; g<4; g++)
      #pragma unroll
      for (int jt=0;jt<4;jt++)
        #pragma unroll
        for (int i=0;i<4;i++)
          acc[g][jt][i] = bf2f(Xg[((size_t)pos*B_ + (rg*4+i))*G4_ + w*256 + g*64 + jt*16 + col]);
    #pragma unroll
    for (int kh=0;kh<2;kh++){
      bf16x8 af[8];
      #pragma unroll
      for (int kt=0;kt<8;kt++){
        int addr = (albase + (kh*8+kt)*64) ^ axmask;
        af[kt] = *(const bf16x8*)((const char*)hls + cur*16384 + addr);
      }
      #pragma unroll
      for (int g=0;g<4;g++){
        #pragma unroll
        for (int jt=0;jt<4;jt++){
          const ushort* Bp = Whh + ((size_t)(w*256 + g*64 + jt*16 + col))*H_ + kh*256 + rg*8;
          #pragma unroll
          for (int kt=0;kt<8;kt++)
            acc[g][jt] = mfma16(af[kt], *(const bf16x8*)(Bp + kt*32), acc[g][jt]);
        }
      }
    }
    int nxt = cur ^ 1;
    #pragma unroll
    for (int jt=0;jt<4;jt++){
      #pragma unroll
      for (int i=0;i<4;i++){
        float zi = acc[0][jt][i], zf = acc[1][jt][i], zg = acc[2][jt][i], zo = acc[3][jt][i];
        float cc = fsig(zf)*cst[jt*4+i] + fsig(zi)*ftanh(zg);
        cst[jt*4+i] = cc;
        float h = fsig(zo)*ftanh(cc);
        int b_i = rg*4+i;
        int j = w*64 + jt*16 + col;
        ushort hb = f2bf(h);
        enc[((size_t)b_i*S_ + pos)*H2_ + dir*H_ + j] = hb;
        int wb = ((b_i<<10) + (j<<1)) ^ ((b_i&7)<<4);
        *(ushort*)((char*)hls + nxt*16384 + wb) = hb;
        if (t == S_-1){
          xi[b_i*KXI_ + E_ + H2_ + dir*H_ + j] = hb;   // decoder h0
          cbuf[b_i*H2_ + dir*H_ + j] = cc;             // decoder c0
        }
      }
    }
    __syncthreads();
    cur = nxt;
  }
}

// ---------------- decoder attention: scores[b,s] = sum_k tanh(P + q) ----------------
__global__ __launch_bounds__(256) void k_scores(const float* __restrict__ P, const float* __restrict__ q,
    float* __restrict__ scores){
  int r = blockIdx.x*4 + (threadIdx.x>>6);
  int lane = threadIdx.x&63;
  int b = r>>9;
  const float4* Pr = (const float4*)(P + (size_t)r*H2_) + lane*4;
  const float4* qr = (const float4*)(q + (size_t)b*H2_) + lane*4;
  float s = 0.f;
  #pragma unroll
  for (int u=0;u<4;u++){
    float4 pv = Pr[u], qv = qr[u];
    s += ftanh(pv.x+qv.x) + ftanh(pv.y+qv.y) + ftanh(pv.z+qv.z) + ftanh(pv.w+qv.w);
  }
  #pragma unroll
  for (int o=32;o;o>>=1) s += __shfl_xor(s, o);
  if (lane==0) scores[r] = s;
}

// ---------------- softmax over s + ctx = w @ enc_out, fill xi = [x | ctx | h] ----------------
__global__ __launch_bounds__(512) void k_attn_ctx(const float* __restrict__ scores, const ushort* __restrict__ enc,
    const ushort* __restrict__ DXb, ushort* __restrict__ xi, int t){
  __shared__ float wls[512];
  __shared__ float red[16];
  int b = blockIdx.x, tid = threadIdx.x;
  int w = tid>>6, lane = tid&63;
  float sc = scores[b*S_ + tid];
  float m = sc;
  #pragma unroll
  for (int o=32;o;o>>=1) m = fmaxf(m, __shfl_xor(m,o));
  if (lane==0) red[w] = m;
  __syncthreads();
  if (tid==0){ float mm = red[0]; for (int i2=1;i2<8;i2++) mm = fmaxf(mm, red[i2]); red[8] = mm; }
  __syncthreads();
  float M = red[8];
  float e = __builtin_amdgcn_exp2f((sc - M)*1.4426950408889634f);
  float ssum = e;
  #pragma unroll
  for (int o=32;o;o>>=1) ssum += __shfl_xor(ssum,o);
  if (lane==0) red[w] = ssum;
  __syncthreads();
  if (tid==0){ float s2 = 0.f; for (int i2=0;i2<8;i2++) s2 += red[i2]; red[9] = __builtin_amdgcn_rcpf(s2); }
  __syncthreads();
  wls[tid] = e * red[9];
  __syncthreads();
  float a0=0.f, a1=0.f;
  const ushort* eb = enc + (size_t)b*S_*H2_;
  for (int s2=0;s2<S_;s2++){
    float wv = wls[s2];
    a0 += wv * bf2f(eb[(size_t)s2*H2_ + tid]);
    a1 += wv * bf2f(eb[(size_t)s2*H2_ + 512 + tid]);
  }
  xi[b*KXI_ + E_ + tid]       = f2bf(a0);
  xi[b*KXI_ + E_ + 512 + tid] = f2bf(a1);
  if (tid < E_) xi[b*KXI_ + tid] = DXb[((size_t)t*B_ + b)*E_ + tid];
}

// ---------------- decoder LSTM cell ----------------
__global__ void k_cell(const float* __restrict__ gates, float* __restrict__ cbuf,
                       ushort* __restrict__ xi, ushort* __restrict__ hsd, int t){
  int idx = blockIdx.x*256 + threadIdx.x;   // 16384 = B*H2
  int b = idx>>10, j = idx&1023;
  const float* gr = gates + (size_t)b*D4_;
  float zi = gr[j], zf = gr[H2_+j], zg = gr[2*H2_+j], zo = gr[3*H2_+j];
  float cc = fsig(zf)*cbuf[idx] + fsig(zi)*ftanh(zg);
  cbuf[idx] = cc;
  float h = fsig(zo)*ftanh(cc);
  ushort hb = f2bf(h);
  xi[b*KXI_ + E_ + H2_ + j] = hb;
  hsd[((size_t)t*B_ + b)*H2_ + j] = hb;
}

extern "C" void kernel_launch(void* const* d_in, const int* in_sizes, int n_in,
                              void* d_out, int out_size, void* d_ws, size_t ws_size,
                              hipStream_t stream) {
  const int* src   = (const int*)d_in[0];
  const int* tgt   = (const int*)d_in[1];
  const float* emb   = (const float*)d_in[2];
  const float* Wih_f = (const float*)d_in[3];
  const float* Whh_f = (const float*)d_in[4];
  const float* bih_f = (const float*)d_in[5];
  const float* bhh_f = (const float*)d_in[6];
  const float* Wih_b = (const float*)d_in[7];
  const float* Whh_b = (const float*)d_in[8];
  const float* bih_b = (const float*)d_in[9];
  const float* bhh_b = (const float*)d_in[10];
  const float* Wih_d = (const float*)d_in[11];
  const float* Whh_d = (const float*)d_in[12];
  const float* bih_d = (const float*)d_in[13];
  const float* bhh_d = (const float*)d_in[14];
  const float* Wa    = (const float*)d_in[15];
  const float* ba    = (const float*)d_in[16];
  const float* Wo    = (const float*)d_in[17];
  const float* bo    = (const float*)d_in[18];
  float* out = (float*)d_out;
  (void)in_sizes; (void)n_in; (void)out_size; (void)ws_size;

  char* ws = (char*)d_ws;
  size_t off = 0;
  auto alloc = [&](size_t bytes)->char*{ char* p = ws + off; off += (bytes + 255) & ~(size_t)255; return p; };
  ushort* Xb     = (ushort*)alloc((size_t)S_*B_*E_*2);
  ushort* DXb    = (ushort*)alloc((size_t)DSTEPS*B_*E_*2);
  ushort* Wihf_p = (ushort*)alloc((size_t)G4_*E_*2);
  ushort* Wihb_p = (ushort*)alloc((size_t)G4_*E_*2);
  ushort* Whhf_p = (ushort*)alloc((size_t)G4_*H_*2);
  ushort* Whhb_p = (ushort*)alloc((size_t)G4_*H_*2);
  float*  bsf    = (float*)alloc(G4_*4);
  float*  bsb    = (float*)alloc(G4_*4);
  ushort* ENC    = (ushort*)alloc((size_t)B_*S_*H2_*2);
  ushort* WaH    = (ushort*)alloc((size_t)H2_*H2_*2);
  ushort* WaE    = (ushort*)alloc((size_t)H2_*H2_*2);
  ushort* Wd     = (ushort*)alloc((size_t)D4_*KXI_*2);
  float*  bsd    = (float*)alloc(D4_*4);
  ushort* WoB    = (ushort*)alloc((size_t)V_*H2_*2);
  float*  cbuf   = (float*)alloc(B_*H2_*4);
  ushort* xi     = (ushort*)alloc(B_*KXI_*2);
  float*  qbuf   = (float*)alloc(B_*H2_*4);
  float*  scores = (float*)alloc(B_*S_*4);
  float*  gates  = (float*)alloc(B_*D4_*4);
  ushort* hsd    = (ushort*)alloc((size_t)MD*H2_*2);
  char*   big    = alloc((size_t)2*S_*B_*G4_*2);   // Xgf+Xgb; later aliased by P (f32)
  ushort* Xgf = (ushort*)big;
  ushort* Xgb = (ushort*)(big + (size_t)S_*B_*G4_*2);
  float*  P   = (float*)big;

  // ---- setup ----
  k_embed<<<dim3(S_*B_ + DSTEPS*B_), dim3(E_), 0, stream>>>(src, tgt, emb, Xb, DXb);
  k_cvt_encw<<<dim3(G4_), dim3(256), 0, stream>>>(Wih_f, Wihf_p, E_);
  k_cvt_encw<<<dim3(G4_), dim3(256), 0, stream>>>(Wih_b, Wihb_p, E_);
  k_cvt_encw<<<dim3(G4_), dim3(256), 0, stream>>>(Whh_f, Whhf_p, H_);
  k_cvt_encw<<<dim3(G4_), dim3(256), 0, stream>>>(Whh_b, Whhb_p, H_);
  k_bias_encp<<<dim3(8), dim3(256), 0, stream>>>(bih_f, bhh_f, bsf);
  k_bias_encp<<<dim3(8), dim3(256), 0, stream>>>(bih_b, bhh_b, bsb);
  k_cvt_strided<<<dim3(H2_), dim3(256), 0, stream>>>(Wa, WaH, H2_, 2*H2_, 0,   H2_, 0);
  k_cvt_strided<<<dim3(H2_), dim3(256), 0, stream>>>(Wa, WaE, H2_, 2*H2_, H2_, H2_, 0);
  k_cvt_strided<<<dim3(D4_), dim3(256), 0, stream>>>(Wih_d, Wd, E_+H2_, E_+H2_, 0, KXI_, 0);
  k_cvt_strided<<<dim3(D4_), dim3(256), 0, stream>>>(Whh_d, Wd, H2_, H2_, 0, KXI_, E_+H2_);
  k_cvt_strided<<<dim3(V_),  dim3(256), 0, stream>>>(Wo, WoB, H2_, H2_, 0, H2_, 0);
  k_addb<<<dim3(16), dim3(256), 0, stream>>>(bih_d, bhh_d, bsd, D4_);

  // ---- encoder input-gate pre-GEMMs: Xg = Xb @ Wih^T + (bih+bhh), bf16 out ----
  gemm128<1><<<dim3(G4_/128, (S_*B_)/128), dim3(256), 0, stream>>>(Xb, Wihf_p, bsf, Xgf, S_*B_, G4_, E_, 0);
  gemm128<1><<<dim3(G4_/128, (S_*B_)/128), dim3(256), 0, stream>>>(Xb, Wihb_p, bsb, Xgb, S_*B_, G4_, E_, 0);

  // ---- bidirectional encoder (persistent, 2 WGs) ----
  k_encoder<<<dim3(2), dim3(512), 0, stream>>>(Xgf, Xgb, Whhf_p, Whhb_p, ENC, xi, cbuf);

  // ---- enc_proj = enc_out @ Wa_e^T + ba  (f32 out, aliases Xgf space) ----
  gemm128<0><<<dim3(H2_/128, (B_*S_)/128), dim3(256), 0, stream>>>(ENC, WaE, ba, P, B_*S_, H2_, H2_, 0);
  k_zero_t0<<<dim3((B_*V_+255)/256), dim3(256), 0, stream>>>(out);

  // ---- decoder: 127 sequential steps ----
  for (int t=0;t<DSTEPS;t++){
    k_smallm<<<dim3(H2_/32), dim3(128), 0, stream>>>(xi + E_+H2_, KXI_, WaH, nullptr, qbuf, H2_, H2_, H2_);
    k_scores<<<dim3((B_*S_)/4), dim3(256), 0, stream>>>(P, qbuf, scores);
    k_attn_ctx<<<dim3(B_), dim3(512), 0, stream>>>(scores, ENC, DXb, xi, t);
    k_smallm<<<dim3(D4_/32), dim3(128), 0, stream>>>(xi, KXI_, Wd, bsd, gates, D4_, D4_, KXI_);
    k_cell<<<dim3((B_*H2_)/256), dim3(256), 0, stream>>>(gates, cbuf, xi, hsd, t);
  }

  // ---- final projection: preds = hsd @ Wo^T + bo, scattered to out[b, t+1, :] ----
  gemm128<2><<<dim3(V_/128, MD/128), dim3(256), 0, stream>>>(hsd, WoB, bo, out, MD, V_, H2_, DSTEPS*B_);
}

// Round 2
// 25679.260 us; speedup vs baseline: 1.4296x; 1.4296x over previous
//
#include <hip/hip_runtime.h>

typedef unsigned int uint;
typedef unsigned short ushort;
typedef __attribute__((ext_vector_type(8))) short bf16x8;
typedef __attribute__((ext_vector_type(4))) float f32x4;

static constexpr int V_ = 32000, E_ = 256, H_ = 512, B_ = 16, S_ = 512, T_ = 128;
static constexpr int H2_ = 1024, G4_ = 2048, D4_ = 4096, KXI_ = 2304; // 256+1024+1024
static constexpr int DSTEPS = T_ - 1;  // 127
static constexpr int MD = 2048;        // padded rows for preds GEMM (2032 valid)
static constexpr int NWG_DEC = 128;
static constexpr float LOG2E = 1.4426950408889634f;

#define DEVFN __device__ __forceinline__

DEVFN ushort f2bf(float f){ uint u = __builtin_bit_cast(uint, f); u += 0x7fffu + ((u>>16)&1u); return (ushort)(u>>16); }
DEVFN float bf2f(ushort h){ uint u = ((uint)h)<<16; return __builtin_bit_cast(float, u); }
DEVFN float fsig(float x){ float e = __builtin_amdgcn_exp2f(-LOG2E*x); return __builtin_amdgcn_rcpf(1.f+e); }
DEVFN float ftanh(float x){ x = fminf(15.f,fmaxf(-15.f,x)); float e = __builtin_amdgcn_exp2f(2.f*LOG2E*x); return (e-1.f)*__builtin_amdgcn_rcpf(e+1.f); }
DEVFN f32x4 mfma16(bf16x8 a, bf16x8 b, f32x4 c){ return __builtin_amdgcn_mfma_f32_16x16x32_bf16(a,b,c,0,0,0); }

// device-scope sense-reversing grid barrier (participants = nwg workgroups)
DEVFN void gridbar(uint* cnt, uint* gen, uint nwg, int tid){
  __syncthreads();
  if (tid==0){
    __threadfence();
    uint g = __hip_atomic_load(gen, __ATOMIC_RELAXED, __HIP_MEMORY_SCOPE_AGENT);
    uint a = __hip_atomic_fetch_add(cnt, 1u, __ATOMIC_ACQ_REL, __HIP_MEMORY_SCOPE_AGENT);
    if (a == nwg-1u){
      __hip_atomic_store(cnt, 0u, __ATOMIC_RELAXED, __HIP_MEMORY_SCOPE_AGENT);
      __hip_atomic_fetch_add(gen, 1u, __ATOMIC_RELEASE, __HIP_MEMORY_SCOPE_AGENT);
    } else {
      while (__hip_atomic_load(gen, __ATOMIC_RELAXED, __HIP_MEMORY_SCOPE_AGENT) == g)
        __builtin_amdgcn_s_sleep(2);
    }
    __threadfence();
  }
  __syncthreads();
}

// zero barrier flags + h exchange buffers
__global__ void k_init(uint* __restrict__ flags, ushort* __restrict__ hgf, ushort* __restrict__ hgb){
  int i = blockIdx.x*256 + threadIdx.x;
  if (i < 8) flags[i] = 0;
  if (i < 2*B_*H_){ hgf[i]=0; hgb[i]=0; }
}

// ---------------- embedding gather (src -> Xb bf16, tgt -> DXb bf16) ----------------
__global__ void k_embed(const int* __restrict__ src, const int* __restrict__ tgt,
                        const float* __restrict__ emb, ushort* __restrict__ Xb, ushort* __restrict__ DXb){
  int r = blockIdx.x, tid = threadIdx.x;
  if (r < S_*B_){
    int s = r>>4, b = r&15;
    int id = src[b*S_+s];
    Xb[(size_t)r*E_+tid] = f2bf(emb[(size_t)id*E_+tid]);
  } else {
    int r2 = r - S_*B_;
    int t = r2>>4, b = r2&15;
    int id = tgt[b*T_+t];
    DXb[(size_t)r2*E_+tid] = f2bf(emb[(size_t)id*E_+tid]);
  }
}

// encoder Wih convert with per-WG gate permutation:
// dst row d: wg=d>>6, r=d&63, w=r>>5, jj=(r>>2)&7, g=r&3 -> src row g*512 + wg*16 + w*8 + jj
__global__ void k_cvt_encw(const float* __restrict__ src, ushort* __restrict__ dst){
  int d = blockIdx.x;
  int wg = d>>6, r = d&63;
  int w = r>>5, jj=(r>>2)&7, g=r&3;
  int srow = g*H_ + wg*16 + w*8 + jj;
  for (int c = threadIdx.x; c < E_; c += 256)
    dst[(size_t)d*E_ + c] = f2bf(src[(size_t)srow*E_ + c]);
}

__global__ void k_bias_encp(const float* __restrict__ bih, const float* __restrict__ bhh, float* __restrict__ dst){
  int d = blockIdx.x*256 + threadIdx.x;
  int wg = d>>6, r = d&63;
  int w = r>>5, jj=(r>>2)&7, g=r&3;
  int srow = g*H_ + wg*16 + w*8 + jj;
  dst[d] = bih[srow]+bhh[srow];
}

// decoder Wd convert (permuted): dst row d: wg=d>>6, r=d&63, w=r>>4, jj=(r>>2)&3, g=r&3
// src row = g*1024 + wg*16 + w*4 + jj ; cols [0,1280)=Wih_d, [1280,2304)=Whh_d
__global__ void k_cvt_decw(const float* __restrict__ Wih_d, const float* __restrict__ Whh_d,
                           ushort* __restrict__ dst){
  int d = blockIdx.x;
  int wg = d>>6, r = d&63;
  int w = r>>4, jj=(r>>2)&3, g=r&3;
  int srow = g*H2_ + wg*16 + w*4 + jj;
  for (int c = threadIdx.x; c < KXI_; c += 256){
    float v = (c < E_+H2_) ? Wih_d[(size_t)srow*(E_+H2_) + c] : Whh_d[(size_t)srow*H2_ + (c - (E_+H2_))];
    dst[(size_t)d*KXI_ + c] = f2bf(v);
  }
}

__global__ void k_bias_decp(const float* __restrict__ bih, const float* __restrict__ bhh, float* __restrict__ dst){
  int d = blockIdx.x*256 + threadIdx.x;
  int wg = d>>6, r = d&63;
  int w = r>>4, jj=(r>>2)&3, g=r&3;
  int srow = g*H2_ + wg*16 + w*4 + jj;
  dst[d] = bih[srow]+bhh[srow];
}

__global__ void k_cvt_strided(const float* __restrict__ src, ushort* __restrict__ dst,
                              int cols, int sld, int soff, int dld, int doff){
  int r = blockIdx.x;
  for (int c = threadIdx.x; c < cols; c += 256)
    dst[(size_t)r*dld + doff + c] = f2bf(src[(size_t)r*sld + soff + c]);
}

__global__ void k_zero_t0(float* __restrict__ out){
  int i = blockIdx.x*256 + threadIdx.x;
  if (i < B_*V_){ int b = i / V_, v = i - b*V_; out[(size_t)b*T_*V_ + v] = 0.f; }
}

// ---------------- 128x128-tile bf16 MFMA GEMM: C[M,N] = A[MxK] @ B[NxK]^T + bias ----------------
template<int MODE>
__global__ __launch_bounds__(256) void gemm128(const ushort* __restrict__ A, const ushort* __restrict__ Bm,
    const float* __restrict__ bias, void* __restrict__ outp, int M, int N, int K, int Mvalid){
  __shared__ __align__(16) ushort As[128*32];
  __shared__ __align__(16) ushort Bs[128*32];
  int tid = threadIdx.x;
  int wave = tid>>6, lane = tid&63;
  int m0 = blockIdx.y*128, n0 = blockIdx.x*128;
  int wm = wave>>1, wn = wave&1;
  int col = lane&15, rg = lane>>4;
  f32x4 acc[4][4];
  #pragma unroll
  for (int i=0;i<4;i++)
    #pragma unroll
    for (int j=0;j<4;j++) acc[i][j] = {0.f,0.f,0.f,0.f};
  for (int k0=0;k0<K;k0+=32){
    __syncthreads();
    #pragma unroll
    for (int j=0;j<2;j++){
      int li = j*256+tid;
      int row = li>>2, ko = (li&3)*8;
      *(bf16x8*)(As + li*8) = *(const bf16x8*)(A + (size_t)(m0+row)*K + k0 + ko);
      *(bf16x8*)(Bs + li*8) = *(const bf16x8*)(Bm + (size_t)(n0+row)*K + k0 + ko);
    }
    __syncthreads();
    bf16x8 af[4], bfr[4];
    #pragma unroll
    for (int f=0;f<4;f++){
      af[f]  = *(const bf16x8*)(As + (wm*64+f*16+col)*32 + rg*8);
      bfr[f] = *(const bf16x8*)(Bs + (wn*64+f*16+col)*32 + rg*8);
    }
    #pragma unroll
    for (int fm=0;fm<4;fm++)
      #pragma unroll
      for (int fn=0;fn<4;fn++)
        acc[fm][fn] = mfma16(af[fm], bfr[fn], acc[fm][fn]);
  }
  #pragma unroll
  for (int fm=0;fm<4;fm++){
    int mrow = m0 + wm*64 + fm*16 + rg*4;
    #pragma unroll
    for (int fn=0;fn<4;fn++){
      int gcol = n0 + wn*64 + fn*16 + col;
      float bv = bias ? bias[gcol] : 0.f;
      #pragma unroll
      for (int i=0;i<4;i++){
        float v = acc[fm][fn][i] + bv;
        int grow = mrow + i;
        if (MODE==0) ((float*)outp)[(size_t)grow*N + gcol] = v;
        else if (MODE==1) ((ushort*)outp)[(size_t)grow*N + gcol] = f2bf(v);
        else { if (grow < Mvalid){ int b = grow&15, t = grow>>4;
               ((float*)outp)[(size_t)b*T_*V_ + (size_t)(t+1)*V_ + gcol] = v; } }
      }
    }
  }
}

// ---------------- persistent bidirectional encoder: 32 WGs/dir, Whh slice in LDS ----------------
__global__ __launch_bounds__(128) void k_enc_persist(
    const ushort* __restrict__ Xgf, const ushort* __restrict__ Xgb,
    const float* __restrict__ Whhf, const float* __restrict__ Whhb,
    ushort* __restrict__ enc, ushort* __restrict__ xi, float* __restrict__ cbuf,
    ushort* __restrict__ hgf, ushort* __restrict__ hgb,
    uint* __restrict__ flags){
  const int dir = blockIdx.x >> 5;
  const int wg  = blockIdx.x & 31;
  const ushort* Xg = dir ? Xgb : Xgf;
  const float* Whh = dir ? Whhb : Whhf;
  ushort* hg = dir ? hgb : hgf;
  uint* cnt = flags + dir*2; uint* gen = flags + dir*2 + 1;
  __shared__ __align__(16) ushort Wlds[64*512];   // 64 KiB, XOR-swizzled
  int tid = threadIdx.x;
  // stage Whh slice (64 permuted rows x 512) f32->bf16 into LDS
  for (int r = 0; r < 64; ++r){
    int w_ = r>>5, jj = (r>>2)&7, g = r&3;
    int srow = g*H_ + wg*16 + w_*8 + jj;
    float4 v = *(const float4*)(Whh + (size_t)srow*H_ + tid*4);
    ushort4 o; o.x=f2bf(v.x); o.y=f2bf(v.y); o.z=f2bf(v.z); o.w=f2bf(v.w);
    int byte = (r*1024 + tid*8) ^ ((r&7)<<4);
    *(ushort4*)((char*)Wlds + byte) = o;
  }
  __syncthreads();
  int w = tid>>6, lane = tid&63, colL = lane&15, rg = lane>>4;
  int gg = colL&3;
  float cst[8];
  #pragma unroll
  for (int i=0;i<8;i++) cst[i]=0.f;
  for (int t=0;t<S_;++t){
    int pos = dir ? (S_-1-t) : t;
    const ushort* hsrc = hg + (t&1)*B_*H_;
    bf16x8 af[16];
    #pragma unroll
    for (int kt=0;kt<16;kt++)
      af[kt] = *(const bf16x8*)(hsrc + colL*H_ + rg*8 + kt*32);
    f32x4 acc[2];
    #pragma unroll
    for (int tile=0;tile<2;tile++)
      #pragma unroll
      for (int i=0;i<4;i++)
        acc[tile][i] = bf2f(Xg[((size_t)pos*B_ + rg*4+i)*G4_ + wg*64 + w*32 + tile*16 + colL]);
    #pragma unroll
    for (int tile=0;tile<2;tile++){
      int rowb = w*32 + tile*16 + colL;
      int base = rowb*1024 + rg*16;
      int xm = (rowb&7)<<4;
      #pragma unroll
      for (int kt=0;kt<16;kt++){
        bf16x8 bfv = *(const bf16x8*)((const char*)Wlds + ((base + kt*64) ^ xm));
        acc[tile] = mfma16(af[kt], bfv, acc[tile]);
      }
    }
    ushort* hdst = hg + ((t+1)&1)*B_*H_;
    #pragma unroll
    for (int tile=0;tile<2;tile++){
      #pragma unroll
      for (int i=0;i<4;i++){
        float v0 = acc[tile][i];
        float v1 = __shfl_xor(v0, 1);
        float v2 = __shfl_xor(v0, 2);
        float v3 = __shfl_xor(v1, 2);
        float zi = gg==0?v0: gg==1?v1: gg==2?v2: v3;
        float zf = (gg^1)==0?v0: (gg^1)==1?v1: (gg^1)==2?v2: v3;
        float zg = (gg^2)==0?v0: (gg^2)==1?v1: (gg^2)==2?v2: v3;
        float zo = (gg^3)==0?v0: (gg^3)==1?v1: (gg^3)==2?v2: v3;
        float cc = fsig(zf)*cst[tile*4+i] + fsig(zi)*ftanh(zg);
        cst[tile*4+i] = cc;
        float h = fsig(zo)*ftanh(cc);
        if (gg==0){
          int j = wg*16 + w*8 + tile*4 + (colL>>2);
          int b = rg*4+i;
          ushort hb = f2bf(h);
          enc[((size_t)b*S_ + pos)*H2_ + dir*H_ + j] = hb;
          hdst[b*H_ + j] = hb;
          if (t==S_-1){
            xi[b*KXI_ + E_ + H2_ + dir*H_ + j] = hb;
            cbuf[b*H2_ + dir*H_ + j] = cc;
          }
        }
      }
    }
    if (t != S_-1) gridbar(cnt, gen, 32, tid);
  }
}

// ---------------- persistent decoder: 128 WGs, 4 barriers/step ----------------
__global__ __launch_bounds__(256) void k_dec_persist(
    const float* __restrict__ P, const ushort* __restrict__ WaH,
    const ushort* __restrict__ Wd, const float* __restrict__ bsd,
    const ushort* __restrict__ enc, const ushort* __restrict__ DXb,
    ushort* __restrict__ xi, float* __restrict__ cbuf,
    float* __restrict__ qbuf, float* __restrict__ scores,
    ushort* __restrict__ hsd, uint* __restrict__ flags){
  uint* cnt = flags+4; uint* gen = flags+5;
  int wgid = blockIdx.x, tid = threadIdx.x;
  int w = tid>>6, lane = tid&63, colL = lane&15, rg = lane>>4;
  __shared__ float wls[512];
  __shared__ float redL[16];
  __shared__ float cpart[256];
  for (int t=0;t<DSTEPS;t++){
    // ---- phase A: q = h @ WaH^T (WGs 0..15) ----
    if (wgid < 16){
      int n0 = (wgid*4 + w)*16;
      f32x4 acc = {0.f,0.f,0.f,0.f};
      const ushort* Ap = xi + colL*KXI_ + E_ + H2_ + rg*8;
      const ushort* Bp = WaH + (size_t)(n0+colL)*H2_ + rg*8;
      #pragma unroll 4
      for (int k=0;k<H2_;k+=32)
        acc = mfma16(*(const bf16x8*)(Ap+k), *(const bf16x8*)(Bp+k), acc);
      #pragma unroll
      for (int i=0;i<4;i++)
        qbuf[(size_t)(rg*4+i)*H2_ + n0 + colL] = acc[i];
    }
    gridbar(cnt,gen,NWG_DEC,tid);
    // ---- phase B: scores[r] = sum_k tanh(P[r,k] + q[b,k]) ----
    {
      int r = wgid*64 + w*16;
      for (int rr=0;rr<16;rr++,r++){
        int b = r>>9;
        const float4* Pr = (const float4*)(P + (size_t)r*H2_) + lane*4;
        const float4* qr = (const float4*)(qbuf + (size_t)b*H2_) + lane*4;
        float s = 0.f;
        #pragma unroll
        for (int u=0;u<4;u++){
          float4 pv = Pr[u], qv = qr[u];
          s += ftanh(pv.x+qv.x)+ftanh(pv.y+qv.y)+ftanh(pv.z+qv.z)+ftanh(pv.w+qv.w);
        }
        #pragma unroll
        for (int o=32;o;o>>=1) s += __shfl_xor(s,o);
        if (lane==0) scores[r]=s;
      }
    }
    gridbar(cnt,gen,NWG_DEC,tid);
    // ---- phase C: softmax + ctx (WG = (b, k-chunk of 128)) ----
    {
      int b = wgid>>3, kc = wgid&7;
      float s1 = scores[b*S_+tid], s2v = scores[b*S_+256+tid];
      float m = fmaxf(s1,s2v);
      #pragma unroll
      for (int o=32;o;o>>=1) m = fmaxf(m,__shfl_xor(m,o));
      if (lane==0) redL[w]=m;
      __syncthreads();
      m = fmaxf(fmaxf(redL[0],redL[1]),fmaxf(redL[2],redL[3]));
      float e1 = __builtin_amdgcn_exp2f((s1-m)*LOG2E);
      float e2 = __builtin_amdgcn_exp2f((s2v-m)*LOG2E);
      float ss = e1+e2;
      #pragma unroll
      for (int o=32;o;o>>=1) ss += __shfl_xor(ss,o);
      if (lane==0) redL[8+w]=ss;
      __syncthreads();
      float rinv = __builtin_amdgcn_rcpf(redL[8]+redL[9]+redL[10]+redL[11]);
      wls[tid]     = e1*rinv;
      wls[tid+256] = e2*rinv;
      __syncthreads();
      int c = tid&127, sh = tid>>7;
      const ushort* eb = enc + (size_t)b*S_*H2_ + kc*128 + c;
      float a = 0.f;
      for (int s2 = sh*256; s2 < sh*256+256; ++s2)
        a += wls[s2] * bf2f(eb[(size_t)s2*H2_]);
      cpart[tid] = a;
      __syncthreads();
      if (tid < 128)
        xi[b*KXI_ + E_ + kc*128 + tid] = f2bf(cpart[tid] + cpart[tid+128]);
      if (kc==0)
        xi[b*KXI_ + tid] = DXb[((size_t)t*B_ + b)*E_ + tid];
    }
    gridbar(cnt,gen,NWG_DEC,tid);
    // ---- phase D+E: gates + LSTM cell (WGs 0..63) ----
    if (wgid < 64){
      int row0 = wgid*64 + w*16;
      float bv = bsd[row0+colL];
      f32x4 acc = {bv,bv,bv,bv};
      const ushort* Ap = xi + colL*KXI_ + rg*8;
      const ushort* Bp = Wd + (size_t)(row0+colL)*KXI_ + rg*8;
      #pragma unroll 4
      for (int k=0;k<KXI_;k+=32)
        acc = mfma16(*(const bf16x8*)(Ap+k), *(const bf16x8*)(Bp+k), acc);
      int gg = colL&3;
      int j = wgid*16 + w*4 + (colL>>2);
      #pragma unroll
      for (int i=0;i<4;i++){
        float v0 = acc[i];
        float v1 = __shfl_xor(v0,1);
        float v2 = __shfl_xor(v0,2);
        float v3 = __shfl_xor(v1,2);
        float zi = gg==0?v0: gg==1?v1: gg==2?v2: v3;
        float zf = (gg^1)==0?v0: (gg^1)==1?v1: (gg^1)==2?v2: v3;
        float zg = (gg^2)==0?v0: (gg^2)==1?v1: (gg^2)==2?v2: v3;
        float zo = (gg^3)==0?v0: (gg^3)==1?v1: (gg^3)==2?v2: v3;
        int b = rg*4+i;
        float cc = fsig(zf)*cbuf[b*H2_+j] + fsig(zi)*ftanh(zg);
        float h = fsig(zo)*ftanh(cc);
        if (gg==0){
          cbuf[b*H2_+j]=cc;
          ushort hb=f2bf(h);
          xi[b*KXI_+E_+H2_+j]=hb;
          hsd[((size_t)t*B_+b)*H2_+j]=hb;
        }
      }
    }
    if (t != DSTEPS-1) gridbar(cnt,gen,NWG_DEC,tid);
  }
}

extern "C" void kernel_launch(void* const* d_in, const int* in_sizes, int n_in,
                              void* d_out, int out_size, void* d_ws, size_t ws_size,
                              hipStream_t stream) {
  const int* src   = (const int*)d_in[0];
  const int* tgt   = (const int*)d_in[1];
  const float* emb   = (const float*)d_in[2];
  const float* Wih_f = (const float*)d_in[3];
  const float* Whh_f = (const float*)d_in[4];
  const float* bih_f = (const float*)d_in[5];
  const float* bhh_f = (const float*)d_in[6];
  const float* Wih_b = (const float*)d_in[7];
  const float* Whh_b = (const float*)d_in[8];
  const float* bih_b = (const float*)d_in[9];
  const float* bhh_b = (const float*)d_in[10];
  const float* Wih_d = (const float*)d_in[11];
  const float* Whh_d = (const float*)d_in[12];
  const float* bih_d = (const float*)d_in[13];
  const float* bhh_d = (const float*)d_in[14];
  const float* Wa    = (const float*)d_in[15];
  const float* ba    = (const float*)d_in[16];
  const float* Wo    = (const float*)d_in[17];
  const float* bo    = (const float*)d_in[18];
  float* out = (float*)d_out;
  (void)in_sizes; (void)n_in; (void)out_size; (void)ws_size;

  char* ws = (char*)d_ws;
  size_t off = 0;
  auto alloc = [&](size_t bytes)->char*{ char* p = ws + off; off += (bytes + 255) & ~(size_t)255; return p; };
  ushort* Xb     = (ushort*)alloc((size_t)S_*B_*E_*2);
  ushort* DXb    = (ushort*)alloc((size_t)DSTEPS*B_*E_*2);
  ushort* Wihf_p = (ushort*)alloc((size_t)G4_*E_*2);
  ushort* Wihb_p = (ushort*)alloc((size_t)G4_*E_*2);
  float*  bsf    = (float*)alloc(G4_*4);
  float*  bsb    = (float*)alloc(G4_*4);
  ushort* ENC    = (ushort*)alloc((size_t)B_*S_*H2_*2);
  ushort* WaH    = (ushort*)alloc((size_t)H2_*H2_*2);
  ushort* WaE    = (ushort*)alloc((size_t)H2_*H2_*2);
  ushort* Wd     = (ushort*)alloc((size_t)D4_*KXI_*2);
  float*  bsd    = (float*)alloc(D4_*4);
  ushort* WoB    = (ushort*)alloc((size_t)V_*H2_*2);
  float*  cbuf   = (float*)alloc(B_*H2_*4);
  ushort* xi     = (ushort*)alloc(B_*KXI_*2);
  float*  qbuf   = (float*)alloc(B_*H2_*4);
  float*  scores = (float*)alloc(B_*S_*4);
  ushort* hsd    = (ushort*)alloc((size_t)MD*H2_*2);
  ushort* hgf    = (ushort*)alloc((size_t)2*B_*H_*2);
  ushort* hgb    = (ushort*)alloc((size_t)2*B_*H_*2);
  uint*   flags  = (uint*)alloc(64);
  char*   big    = alloc((size_t)2*S_*B_*G4_*2);   // Xgf+Xgb; later aliased by P (f32)
  ushort* Xgf = (ushort*)big;
  ushort* Xgb = (ushort*)(big + (size_t)S_*B_*G4_*2);
  float*  P   = (float*)big;

  // ---- setup ----
  k_init<<<dim3(64), dim3(256), 0, stream>>>(flags, hgf, hgb);
  k_embed<<<dim3(S_*B_ + DSTEPS*B_), dim3(E_), 0, stream>>>(src, tgt, emb, Xb, DXb);
  k_cvt_encw<<<dim3(G4_), dim3(256), 0, stream>>>(Wih_f, Wihf_p);
  k_cvt_encw<<<dim3(G4_), dim3(256), 0, stream>>>(Wih_b, Wihb_p);
  k_bias_encp<<<dim3(8), dim3(256), 0, stream>>>(bih_f, bhh_f, bsf);
  k_bias_encp<<<dim3(8), dim3(256), 0, stream>>>(bih_b, bhh_b, bsb);
  k_cvt_strided<<<dim3(H2_), dim3(256), 0, stream>>>(Wa, WaH, H2_, 2*H2_, 0,   H2_, 0);
  k_cvt_strided<<<dim3(H2_), dim3(256), 0, stream>>>(Wa, WaE, H2_, 2*H2_, H2_, H2_, 0);
  k_cvt_decw<<<dim3(D4_), dim3(256), 0, stream>>>(Wih_d, Whh_d, Wd);
  k_bias_decp<<<dim3(16), dim3(256), 0, stream>>>(bih_d, bhh_d, bsd);
  k_cvt_strided<<<dim3(V_),  dim3(256), 0, stream>>>(Wo, WoB, H2_, H2_, 0, H2_, 0);

  // ---- encoder input-gate pre-GEMMs: Xg = Xb @ Wih^T + (bih+bhh), bf16 out (permuted cols) ----
  gemm128<1><<<dim3(G4_/128, (S_*B_)/128), dim3(256), 0, stream>>>(Xb, Wihf_p, bsf, Xgf, S_*B_, G4_, E_, 0);
  gemm128<1><<<dim3(G4_/128, (S_*B_)/128), dim3(256), 0, stream>>>(Xb, Wihb_p, bsb, Xgb, S_*B_, G4_, E_, 0);

  // ---- persistent bidirectional encoder (64 WGs) ----
  k_enc_persist<<<dim3(64), dim3(128), 0, stream>>>(Xgf, Xgb, Whh_f, Whh_b, ENC, xi, cbuf, hgf, hgb, flags);

  // ---- enc_proj = enc_out @ Wa_e^T + ba  (f32 out, aliases Xg space) ----
  gemm128<0><<<dim3(H2_/128, (B_*S_)/128), dim3(256), 0, stream>>>(ENC, WaE, ba, P, B_*S_, H2_, H2_, 0);
  k_zero_t0<<<dim3((B_*V_+255)/256), dim3(256), 0, stream>>>(out);

  // ---- persistent decoder (128 WGs, all 127 steps) ----
  k_dec_persist<<<dim3(NWG_DEC), dim3(256), 0, stream>>>(P, WaH, Wd, bsd, ENC, DXb, xi, cbuf, qbuf, scores, hsd, flags);

  // ---- final projection: preds = hsd @ Wo^T + bo, scattered to out[b, t+1, :] ----
  gemm128<2><<<dim3(V_/128, MD/128), dim3(256), 0, stream>>>(hsd, WoB, bo, out, MD, V_, H2_, DSTEPS*B_);
}

// Round 3
// 13844.122 us; speedup vs baseline: 2.6517x; 1.8549x over previous
//
#include <hip/hip_runtime.h>

typedef unsigned int uint;
typedef unsigned short ushort;
typedef __attribute__((ext_vector_type(8))) short bf16x8;
typedef __attribute__((ext_vector_type(4))) float f32x4;

static constexpr int V_ = 32000, E_ = 256, H_ = 512, B_ = 16, S_ = 512, T_ = 128;
static constexpr int H2_ = 1024, G4_ = 2048, D4_ = 4096, KXI_ = 2304; // 256+1024+1024
static constexpr int DSTEPS = T_ - 1;  // 127
static constexpr int MD = 2048;        // padded rows for preds GEMM (2032 valid)
static constexpr int NWG_DEC = 256;
static constexpr float LOG2E = 1.4426950408889634f;
static constexpr int ASTR = 2312;      // Abuf padded row stride (ushorts)

#define DEVFN __device__ __forceinline__

DEVFN ushort f2bf(float f){ uint u = __builtin_bit_cast(uint, f); u += 0x7fffu + ((u>>16)&1u); return (ushort)(u>>16); }
DEVFN float bf2f(ushort h){ uint u = ((uint)h)<<16; return __builtin_bit_cast(float, u); }
DEVFN float fsig(float x){ float e = __builtin_amdgcn_exp2f(-LOG2E*x); return __builtin_amdgcn_rcpf(1.f+e); }
DEVFN float ftanh(float x){ x = fminf(15.f,fmaxf(-15.f,x)); float e = __builtin_amdgcn_exp2f(2.f*LOG2E*x); return (e-1.f)*__builtin_amdgcn_rcpf(e+1.f); }
DEVFN f32x4 mfma16(bf16x8 a, bf16x8 b, f32x4 c){ return __builtin_amdgcn_mfma_f32_16x16x32_bf16(a,b,c,0,0,0); }

// grid barrier: leader-only relaxed atomics, explicit agent fences (wbL2 / invL2)
DEVFN void gridbar(uint* cnt, uint* gen, uint nwg, int tid){
  __syncthreads();
  if (tid==0){
    __builtin_amdgcn_fence(__ATOMIC_RELEASE, "agent");
    uint g = __hip_atomic_load(gen, __ATOMIC_RELAXED, __HIP_MEMORY_SCOPE_AGENT);
    uint a = __hip_atomic_fetch_add(cnt, 1u, __ATOMIC_RELAXED, __HIP_MEMORY_SCOPE_AGENT);
    if (a == nwg-1u){
      __hip_atomic_store(cnt, 0u, __ATOMIC_RELAXED, __HIP_MEMORY_SCOPE_AGENT);
      __hip_atomic_fetch_add(gen, 1u, __ATOMIC_RELAXED, __HIP_MEMORY_SCOPE_AGENT);
    } else {
      while (__hip_atomic_load(gen, __ATOMIC_RELAXED, __HIP_MEMORY_SCOPE_AGENT) == g)
        __builtin_amdgcn_s_sleep(1);
    }
    __builtin_amdgcn_fence(__ATOMIC_ACQUIRE, "agent");
  }
  __syncthreads();
}

__global__ void k_init(uint* __restrict__ flags, ushort* __restrict__ hgf, ushort* __restrict__ hgb){
  int i = blockIdx.x*256 + threadIdx.x;
  if (i < 8) flags[i] = 0;
  if (i < 2*B_*H_){ hgf[i]=0; hgb[i]=0; }
}

// ---------------- embedding gather ----------------
__global__ void k_embed(const int* __restrict__ src, const int* __restrict__ tgt,
                        const float* __restrict__ emb, ushort* __restrict__ Xb, ushort* __restrict__ DXb){
  int r = blockIdx.x, tid = threadIdx.x;
  if (r < S_*B_){
    int s = r>>4, b = r&15;
    int id = src[b*S_+s];
    Xb[(size_t)r*E_+tid] = f2bf(emb[(size_t)id*E_+tid]);
  } else {
    int r2 = r - S_*B_;
    int t = r2>>4, b = r2&15;
    int id = tgt[b*T_+t];
    DXb[(size_t)r2*E_+tid] = f2bf(emb[(size_t)id*E_+tid]);
  }
}

// encoder Wih convert (gate permuted, unchanged mapping)
__global__ void k_cvt_encw(const float* __restrict__ src, ushort* __restrict__ dst){
  int d = blockIdx.x;
  int wg = d>>6, r = d&63;
  int w = r>>5, jj=(r>>2)&7, g=r&3;
  int srow = g*H_ + wg*16 + w*8 + jj;
  for (int c = threadIdx.x; c < E_; c += 256)
    dst[(size_t)d*E_ + c] = f2bf(src[(size_t)srow*E_ + c]);
}

__global__ void k_bias_encp(const float* __restrict__ bih, const float* __restrict__ bhh, float* __restrict__ dst){
  int d = blockIdx.x*256 + threadIdx.x;
  int wg = d>>6, r = d&63;
  int w = r>>5, jj=(r>>2)&7, g=r&3;
  int srow = g*H_ + wg*16 + w*8 + jj;
  dst[d] = bih[srow]+bhh[srow];
}

// decoder Wd convert: dst row d: wg=d>>4, r=d&15, jj=r>>2, g=r&3 -> src row g*1024 + wg*4 + jj
__global__ void k_cvt_decw(const float* __restrict__ Wih_d, const float* __restrict__ Whh_d,
                           ushort* __restrict__ dst){
  int d = blockIdx.x;
  int wg = d>>4, r = d&15, jj = r>>2, g = r&3;
  int srow = g*H2_ + wg*4 + jj;
  for (int c = threadIdx.x; c < KXI_; c += 256){
    float v = (c < E_+H2_) ? Wih_d[(size_t)srow*(E_+H2_) + c] : Whh_d[(size_t)srow*H2_ + (c - (E_+H2_))];
    dst[(size_t)d*KXI_ + c] = f2bf(v);
  }
}

__global__ void k_bias_decp(const float* __restrict__ bih, const float* __restrict__ bhh, float* __restrict__ dst){
  int d = blockIdx.x*256 + threadIdx.x;
  int wg = d>>4, r = d&15, jj = r>>2, g = r&3;
  int srow = g*H2_ + wg*4 + jj;
  dst[d] = bih[srow]+bhh[srow];
}

__global__ void k_cvt_strided(const float* __restrict__ src, ushort* __restrict__ dst,
                              int cols, int sld, int soff, int dld, int doff){
  int r = blockIdx.x;
  for (int c = threadIdx.x; c < cols; c += 256)
    dst[(size_t)r*dld + doff + c] = f2bf(src[(size_t)r*sld + soff + c]);
}

__global__ void k_zero_t0(float* __restrict__ out){
  int i = blockIdx.x*256 + threadIdx.x;
  if (i < B_*V_){ int b = i / V_, v = i - b*V_; out[(size_t)b*T_*V_ + v] = 0.f; }
}

// ---------------- 128x128-tile bf16 MFMA GEMM: C[M,N] = A[MxK] @ B[NxK]^T + bias ----------------
// MODE 0 f32 out; MODE 1 bf16 out; MODE 2 scatter preds; MODE 3 bf16 out in [s][col][b] layout
template<int MODE>
__global__ __launch_bounds__(256) void gemm128(const ushort* __restrict__ A, const ushort* __restrict__ Bm,
    const float* __restrict__ bias, void* __restrict__ outp, int M, int N, int K, int Mvalid){
  __shared__ __align__(16) ushort As[128*32];
  __shared__ __align__(16) ushort Bs[128*32];
  int tid = threadIdx.x;
  int wave = tid>>6, lane = tid&63;
  int m0 = blockIdx.y*128, n0 = blockIdx.x*128;
  int wm = wave>>1, wn = wave&1;
  int col = lane&15, rg = lane>>4;
  f32x4 acc[4][4];
  #pragma unroll
  for (int i=0;i<4;i++)
    #pragma unroll
    for (int j=0;j<4;j++) acc[i][j] = {0.f,0.f,0.f,0.f};
  for (int k0=0;k0<K;k0+=32){
    __syncthreads();
    #pragma unroll
    for (int j=0;j<2;j++){
      int li = j*256+tid;
      int row = li>>2, ko = (li&3)*8;
      *(bf16x8*)(As + li*8) = *(const bf16x8*)(A + (size_t)(m0+row)*K + k0 + ko);
      *(bf16x8*)(Bs + li*8) = *(const bf16x8*)(Bm + (size_t)(n0+row)*K + k0 + ko);
    }
    __syncthreads();
    bf16x8 af[4], bfr[4];
    #pragma unroll
    for (int f=0;f<4;f++){
      af[f]  = *(const bf16x8*)(As + (wm*64+f*16+col)*32 + rg*8);
      bfr[f] = *(const bf16x8*)(Bs + (wn*64+f*16+col)*32 + rg*8);
    }
    #pragma unroll
    for (int fm=0;fm<4;fm++)
      #pragma unroll
      for (int fn=0;fn<4;fn++)
        acc[fm][fn] = mfma16(af[fm], bfr[fn], acc[fm][fn]);
  }
  #pragma unroll
  for (int fm=0;fm<4;fm++){
    int mrow = m0 + wm*64 + fm*16 + rg*4;
    #pragma unroll
    for (int fn=0;fn<4;fn++){
      int gcol = n0 + wn*64 + fn*16 + col;
      float bv = bias ? bias[gcol] : 0.f;
      #pragma unroll
      for (int i=0;i<4;i++){
        float v = acc[fm][fn][i] + bv;
        int grow = mrow + i;
        if (MODE==0) ((float*)outp)[(size_t)grow*N + gcol] = v;
        else if (MODE==1) ((ushort*)outp)[(size_t)grow*N + gcol] = f2bf(v);
        else if (MODE==3) ((ushort*)outp)[(size_t)(grow>>4)*(16*2048) + gcol*16 + (grow&15)] = f2bf(v);
        else { if (grow < Mvalid){ int b = grow&15, t = grow>>4;
               ((float*)outp)[(size_t)b*T_*V_ + (size_t)(t+1)*V_ + gcol] = v; } }
      }
    }
  }
}

// ---------------- persistent bidirectional encoder ----------------
__global__ __launch_bounds__(128) void k_enc_persist(
    const ushort* __restrict__ Xgf, const ushort* __restrict__ Xgb,
    const float* __restrict__ Whhf, const float* __restrict__ Whhb,
    ushort* __restrict__ enc, ushort* __restrict__ enct,
    ushort* __restrict__ hbuf1, float* __restrict__ cbuf0,
    ushort* __restrict__ hgf, ushort* __restrict__ hgb,
    uint* __restrict__ flags){
  const int dir = blockIdx.x >> 5;
  const int wg  = blockIdx.x & 31;
  const ushort* Xg = dir ? Xgb : Xgf;
  const float* Whh = dir ? Whhb : Whhf;
  ushort* hg = dir ? hgb : hgf;
  uint* cnt = flags + dir*2; uint* gen = flags + dir*2 + 1;
  __shared__ __align__(16) ushort Wlds[64*512];   // 64 KiB, XOR-swizzled
  int tid = threadIdx.x;
  for (int r = 0; r < 64; ++r){
    int w_ = r>>5, jj = (r>>2)&7, g = r&3;
    int srow = g*H_ + wg*16 + w_*8 + jj;
    float4 v = *(const float4*)(Whh + (size_t)srow*H_ + tid*4);
    ushort4 o; o.x=f2bf(v.x); o.y=f2bf(v.y); o.z=f2bf(v.z); o.w=f2bf(v.w);
    int byte = (r*1024 + tid*8) ^ ((r&7)<<4);
    *(ushort4*)((char*)Wlds + byte) = o;
  }
  __syncthreads();
  int w = tid>>6, lane = tid&63, colL = lane&15, rg = lane>>4;
  int gg = colL&3;
  float cst[8];
  #pragma unroll
  for (int i=0;i<8;i++) cst[i]=0.f;
  for (int t=0;t<S_;++t){
    int pos = dir ? (S_-1-t) : t;
    const ushort* hsrc = hg + (t&1)*B_*H_;
    bf16x8 af[16];
    #pragma unroll
    for (int kt=0;kt<16;kt++)
      af[kt] = *(const bf16x8*)(hsrc + colL*H_ + rg*8 + kt*32);
    f32x4 acc[2];
    #pragma unroll
    for (int tile=0;tile<2;tile++){
      int colg = wg*64 + w*32 + tile*16 + colL;
      const ushort* xp = Xg + ((size_t)pos*2048 + colg)*16 + rg*4;
      ushort4 xv = *(const ushort4*)xp;
      acc[tile][0] = bf2f(xv.x); acc[tile][1] = bf2f(xv.y);
      acc[tile][2] = bf2f(xv.z); acc[tile][3] = bf2f(xv.w);
    }
    #pragma unroll
    for (int tile=0;tile<2;tile++){
      int rowb = w*32 + tile*16 + colL;
      int base = rowb*1024 + rg*16;
      int xm = (rowb&7)<<4;
      #pragma unroll
      for (int kt=0;kt<16;kt++){
        bf16x8 bfv = *(const bf16x8*)((const char*)Wlds + ((base + kt*64) ^ xm));
        acc[tile] = mfma16(af[kt], bfv, acc[tile]);
      }
    }
    ushort* hdst = hg + ((t+1)&1)*B_*H_;
    #pragma unroll
    for (int tile=0;tile<2;tile++){
      #pragma unroll
      for (int i=0;i<4;i++){
        float v0 = acc[tile][i];
        float v1 = __shfl_xor(v0, 1);
        float v2 = __shfl_xor(v0, 2);
        float v3 = __shfl_xor(v1, 2);
        float zi = gg==0?v0: gg==1?v1: gg==2?v2: v3;
        float zf = (gg^1)==0?v0: (gg^1)==1?v1: (gg^1)==2?v2: v3;
        float zg = (gg^2)==0?v0: (gg^2)==1?v1: (gg^2)==2?v2: v3;
        float zo = (gg^3)==0?v0: (gg^3)==1?v1: (gg^3)==2?v2: v3;
        float cc = fsig(zf)*cst[tile*4+i] + fsig(zi)*ftanh(zg);
        cst[tile*4+i] = cc;
        float h = fsig(zo)*ftanh(cc);
        if (gg==0){
          int j = wg*16 + w*8 + tile*4 + (colL>>2);
          int b = rg*4+i;
          ushort hb = f2bf(h);
          enc[((size_t)b*S_ + pos)*H2_ + dir*H_ + j] = hb;
          enct[((size_t)b*H2_ + dir*H_ + j)*S_ + pos] = hb;
          hdst[b*H_ + j] = hb;
          if (t==S_-1){
            hbuf1[b*H2_ + dir*H_ + j] = hb;   // decoder h0 (slot 1)
            cbuf0[b*H2_ + dir*H_ + j] = cc;   // decoder c0
          }
        }
      }
    }
    if (t != S_-1) gridbar(cnt, gen, 32, tid);
  }
}

// ---------------- persistent decoder: 256 WGs x 512 threads, 4 phases/step ----------------
__global__ __launch_bounds__(512) void k_dec(
    const float* __restrict__ P, const ushort* __restrict__ WaH,
    const ushort* __restrict__ Wd, const float* __restrict__ bsd,
    const ushort* __restrict__ enct, const ushort* __restrict__ DXb,
    const float* __restrict__ cbuf0, ushort* __restrict__ hbuf,
    ushort* __restrict__ ctxbuf, float* __restrict__ qbuf,
    float* __restrict__ scores, ushort* __restrict__ hsd,
    uint* __restrict__ flags){
  __shared__ __align__(16) ushort AB[16*ASTR];   // 74KB: phase-A h-stage / phase-D xi-stage
  __shared__ __align__(16) float pr[8*256];
  __shared__ float redz[256];
  __shared__ float wls[512];
  __shared__ float part[512];
  __shared__ float red[16];
  __shared__ float cst[64];
  uint* cnt = flags+4; uint* gen = flags+5;
  int wgid = blockIdx.x, tid = threadIdx.x;
  int w = tid>>6, lane = tid&63, colL = lane&15, rg = lane>>4;
  if (tid < 64){
    int jj = tid>>4, b = tid&15;
    cst[tid] = cbuf0[b*H2_ + wgid*4 + jj];
  }
  for (int st=0; st<DSTEPS; ++st){
    const ushort* hprev = hbuf + ((st+1)&1)*B_*H2_;
    // ---- phase A: q = h_{t-1} @ WaH^T  (WGs 0..63, k-split over 8 waves) ----
    if (wgid < 64){
      #pragma unroll
      for (int k2=0;k2<4;k2++){
        int idx = tid + k2*512;          // 2048 ushort8 = 16x1024
        int row = idx>>7, seg = idx&127;
        *(bf16x8*)&AB[row*1032 + seg*8] = *(const bf16x8*)(hprev + row*H2_ + seg*8);
      }
      __syncthreads();
      int n0 = wgid*16;
      f32x4 acc = {0.f,0.f,0.f,0.f};
      const ushort* Bp = WaH + (size_t)(n0+colL)*H2_ + w*128 + rg*8;
      #pragma unroll
      for (int kt=0;kt<4;kt++){
        bf16x8 afv = *(const bf16x8*)&AB[colL*1032 + w*128 + kt*32 + rg*8];
        acc = mfma16(afv, *(const bf16x8*)(Bp + kt*32), acc);
      }
      *(f32x4*)&pr[w*256 + lane*4] = acc;
      __syncthreads();
      if (tid < 256){
        float s = pr[tid];
        #pragma unroll
        for (int w8=1;w8<8;w8++) s += pr[w8*256 + tid];
        int l = tid>>2, i = tid&3;
        qbuf[(size_t)((l>>4)*4 + i)*H2_ + n0 + (l&15)] = s;
      }
    }
    gridbar(cnt,gen,NWG_DEC,tid);
    // ---- phase B: scores[b,s] = sum_k tanh(P + q) (4 rows/wave) ----
    {
      int b = wgid>>4, wc = wgid&15;
      float4 qv[4];
      #pragma unroll
      for (int u=0;u<4;u++) qv[u] = *(const float4*)(qbuf + (size_t)b*H2_ + lane*16 + u*4);
      int rbase = b*S_ + wc*32 + w*4;
      #pragma unroll
      for (int rr=0;rr<4;rr++){
        int r = rbase + rr;
        const float4* Pr = (const float4*)(P + (size_t)r*H2_) + lane*4;
        float s = 0.f;
        #pragma unroll
        for (int u=0;u<4;u++){
          float4 pv = Pr[u];
          s += ftanh(pv.x+qv[u].x)+ftanh(pv.y+qv[u].y)+ftanh(pv.z+qv[u].z)+ftanh(pv.w+qv[u].w);
        }
        #pragma unroll
        for (int o=32;o;o>>=1) s += __shfl_xor(s,o);
        if (lane==0) scores[r] = s;
      }
    }
    gridbar(cnt,gen,NWG_DEC,tid);
    // ---- phase C: softmax (replicated per b) + ctx via ENCT ----
    {
      int b = wgid>>4, cc = wgid&15;
      float sc = scores[b*S_ + tid];
      float m = sc;
      #pragma unroll
      for (int o=32;o;o>>=1) m = fmaxf(m, __shfl_xor(m,o));
      if (lane==0) red[w] = m;
      __syncthreads();
      m = red[0];
      #pragma unroll
      for (int k2=1;k2<8;k2++) m = fmaxf(m, red[k2]);
      float e = __builtin_amdgcn_exp2f((sc - m)*LOG2E);
      float ss = e;
      #pragma unroll
      for (int o=32;o;o>>=1) ss += __shfl_xor(ss,o);
      if (lane==0) red[8+w] = ss;
      __syncthreads();
      float tot = red[8];
      #pragma unroll
      for (int k2=9;k2<16;k2++) tot += red[k2];
      wls[tid] = e * __builtin_amdgcn_rcpf(tot);
      __syncthreads();
      int c = cc*64 + (tid&63), sseg = tid>>6;
      const ushort* ep = enct + ((size_t)b*H2_ + c)*S_ + sseg*64;
      float a = 0.f;
      #pragma unroll
      for (int u=0;u<8;u++){
        bf16x8 ev = *(const bf16x8*)(ep + u*8);
        #pragma unroll
        for (int j=0;j<8;j++) a += wls[sseg*64 + u*8 + j] * bf2f((ushort)ev[j]);
      }
      part[tid] = a;
      __syncthreads();
      if (tid < 64){
        float s = part[tid];
        #pragma unroll
        for (int g2=1;g2<8;g2++) s += part[g2*64 + tid];
        ctxbuf[b*H2_ + cc*64 + tid] = f2bf(s);
      }
    }
    gridbar(cnt,gen,NWG_DEC,tid);
    // ---- phase D: gates = [x|ctx|h] @ Wd^T + cell (16 rows/WG, k-split 8x288) ----
    {
      { int b3 = tid>>5, seg = tid&31;
        *(bf16x8*)&AB[b3*ASTR + seg*8] = *(const bf16x8*)(DXb + ((size_t)(st*16+b3))*E_ + seg*8); }
      #pragma unroll
      for (int k2=0;k2<4;k2++){
        int idx = tid + k2*512;
        int row = idx>>7, seg = idx&127;
        *(bf16x8*)&AB[row*ASTR + 256 + seg*8]  = *(const bf16x8*)(ctxbuf + row*H2_ + seg*8);
        *(bf16x8*)&AB[row*ASTR + 1280 + seg*8] = *(const bf16x8*)(hprev + row*H2_ + seg*8);
      }
      __syncthreads();
      int row0 = wgid*16;
      f32x4 acc = {0.f,0.f,0.f,0.f};
      const ushort* Bp = Wd + (size_t)(row0+colL)*KXI_ + w*288 + rg*8;
      #pragma unroll
      for (int kt=0;kt<9;kt++){
        bf16x8 afv = *(const bf16x8*)&AB[colL*ASTR + w*288 + kt*32 + rg*8];
        acc = mfma16(afv, *(const bf16x8*)(Bp + kt*32), acc);
      }
      *(f32x4*)&pr[w*256 + lane*4] = acc;
      __syncthreads();
      if (tid < 256){
        float s = bsd[row0 + ((tid>>2)&15)];
        #pragma unroll
        for (int w8=0;w8<8;w8++) s += pr[w8*256 + tid];
        redz[tid] = s;
      }
      __syncthreads();
      if (tid < 64){
        int jj = tid>>4, b4 = tid&15, rgc = b4>>2, ic = b4&3;
        float zi = redz[((jj*4+0) + 16*rgc)*4 + ic];
        float zf = redz[((jj*4+1) + 16*rgc)*4 + ic];
        float zg = redz[((jj*4+2) + 16*rgc)*4 + ic];
        float zo = redz[((jj*4+3) + 16*rgc)*4 + ic];
        float cc2 = fsig(zf)*cst[tid] + fsig(zi)*ftanh(zg);
        cst[tid] = cc2;
        float h = fsig(zo)*ftanh(cc2);
        ushort hb = f2bf(h);
        int j = wgid*4 + jj;
        (hbuf + (st&1)*B_*H2_)[b4*H2_ + j] = hb;
        hsd[((size_t)st*B_ + b4)*H2_ + j] = hb;
      }
      __syncthreads();
    }
    if (st != DSTEPS-1) gridbar(cnt,gen,NWG_DEC,tid);
  }
}

extern "C" void kernel_launch(void* const* d_in, const int* in_sizes, int n_in,
                              void* d_out, int out_size, void* d_ws, size_t ws_size,
                              hipStream_t stream) {
  const int* src   = (const int*)d_in[0];
  const int* tgt   = (const int*)d_in[1];
  const float* emb   = (const float*)d_in[2];
  const float* Wih_f = (const float*)d_in[3];
  const float* Whh_f = (const float*)d_in[4];
  const float* bih_f = (const float*)d_in[5];
  const float* bhh_f = (const float*)d_in[6];
  const float* Wih_b = (const float*)d_in[7];
  const float* Whh_b = (const float*)d_in[8];
  const float* bih_b = (const float*)d_in[9];
  const float* bhh_b = (const float*)d_in[10];
  const float* Wih_d = (const float*)d_in[11];
  const float* Whh_d = (const float*)d_in[12];
  const float* bih_d = (const float*)d_in[13];
  const float* bhh_d = (const float*)d_in[14];
  const float* Wa    = (const float*)d_in[15];
  const float* ba    = (const float*)d_in[16];
  const float* Wo    = (const float*)d_in[17];
  const float* bo    = (const float*)d_in[18];
  float* out = (float*)d_out;
  (void)in_sizes; (void)n_in; (void)out_size; (void)ws_size;

  char* ws = (char*)d_ws;
  size_t off = 0;
  auto alloc = [&](size_t bytes)->char*{ char* p = ws + off; off += (bytes + 255) & ~(size_t)255; return p; };
  ushort* Xb     = (ushort*)alloc((size_t)S_*B_*E_*2);
  ushort* DXb    = (ushort*)alloc((size_t)DSTEPS*B_*E_*2);
  ushort* Wihf_p = (ushort*)alloc((size_t)G4_*E_*2);
  ushort* Wihb_p = (ushort*)alloc((size_t)G4_*E_*2);
  float*  bsf    = (float*)alloc(G4_*4);
  float*  bsb    = (float*)alloc(G4_*4);
  ushort* ENC    = (ushort*)alloc((size_t)B_*S_*H2_*2);
  ushort* ENCT   = (ushort*)alloc((size_t)B_*S_*H2_*2);
  ushort* WaH    = (ushort*)alloc((size_t)H2_*H2_*2);
  ushort* WaE    = (ushort*)alloc((size_t)H2_*H2_*2);
  ushort* Wd     = (ushort*)alloc((size_t)D4_*KXI_*2);
  float*  bsd    = (float*)alloc(D4_*4);
  ushort* WoB    = (ushort*)alloc((size_t)V_*H2_*2);
  float*  cbuf0  = (float*)alloc(B_*H2_*4);
  ushort* hbuf   = (ushort*)alloc((size_t)2*B_*H2_*2);
  ushort* ctxbuf = (ushort*)alloc((size_t)B_*H2_*2);
  float*  qbuf   = (float*)alloc(B_*H2_*4);
  float*  scores = (float*)alloc(B_*S_*4);
  ushort* hsd    = (ushort*)alloc((size_t)MD*H2_*2);
  ushort* hgf    = (ushort*)alloc((size_t)2*B_*H_*2);
  ushort* hgb    = (ushort*)alloc((size_t)2*B_*H_*2);
  uint*   flags  = (uint*)alloc(64);
  char*   big    = alloc((size_t)2*S_*B_*G4_*2);   // Xg2f+Xg2b; later aliased by P (f32)
  ushort* Xgf = (ushort*)big;
  ushort* Xgb = (ushort*)(big + (size_t)S_*B_*G4_*2);
  float*  P   = (float*)big;

  // ---- setup ----
  k_init<<<dim3(64), dim3(256), 0, stream>>>(flags, hgf, hgb);
  k_embed<<<dim3(S_*B_ + DSTEPS*B_), dim3(E_), 0, stream>>>(src, tgt, emb, Xb, DXb);
  k_cvt_encw<<<dim3(G4_), dim3(256), 0, stream>>>(Wih_f, Wihf_p);
  k_cvt_encw<<<dim3(G4_), dim3(256), 0, stream>>>(Wih_b, Wihb_p);
  k_bias_encp<<<dim3(8), dim3(256), 0, stream>>>(bih_f, bhh_f, bsf);
  k_bias_encp<<<dim3(8), dim3(256), 0, stream>>>(bih_b, bhh_b, bsb);
  k_cvt_strided<<<dim3(H2_), dim3(256), 0, stream>>>(Wa, WaH, H2_, 2*H2_, 0,   H2_, 0);
  k_cvt_strided<<<dim3(H2_), dim3(256), 0, stream>>>(Wa, WaE, H2_, 2*H2_, H2_, H2_, 0);
  k_cvt_decw<<<dim3(D4_), dim3(256), 0, stream>>>(Wih_d, Whh_d, Wd);
  k_bias_decp<<<dim3(16), dim3(256), 0, stream>>>(bih_d, bhh_d, bsd);
  k_cvt_strided<<<dim3(V_),  dim3(256), 0, stream>>>(Wo, WoB, H2_, H2_, 0, H2_, 0);

  // ---- encoder input-gate pre-GEMMs -> [s][col][b] layout (MODE 3) ----
  gemm128<3><<<dim3(G4_/128, (S_*B_)/128), dim3(256), 0, stream>>>(Xb, Wihf_p, bsf, Xgf, S_*B_, G4_, E_, 0);
  gemm128<3><<<dim3(G4_/128, (S_*B_)/128), dim3(256), 0, stream>>>(Xb, Wihb_p, bsb, Xgb, S_*B_, G4_, E_, 0);

  // ---- persistent bidirectional encoder (64 WGs) ----
  k_enc_persist<<<dim3(64), dim3(128), 0, stream>>>(Xgf, Xgb, Whh_f, Whh_b, ENC, ENCT,
                                                    hbuf + B_*H2_, cbuf0, hgf, hgb, flags);

  // ---- enc_proj = enc_out @ Wa_e^T + ba ----
  gemm128<0><<<dim3(H2_/128, (B_*S_)/128), dim3(256), 0, stream>>>(ENC, WaE, ba, P, B_*S_, H2_, H2_, 0);
  k_zero_t0<<<dim3((B_*V_+255)/256), dim3(256), 0, stream>>>(out);

  // ---- persistent decoder (256 WGs x 512 threads) ----
  k_dec<<<dim3(NWG_DEC), dim3(512), 0, stream>>>(P, WaH, Wd, bsd, ENCT, DXb, cbuf0, hbuf,
                                                 ctxbuf, qbuf, scores, hsd, flags);

  // ---- final projection ----
  gemm128<2><<<dim3(V_/128, MD/128), dim3(256), 0, stream>>>(hsd, WoB, bo, out, MD, V_, H2_, DSTEPS*B_);
}

// Round 4
// 7043.797 us; speedup vs baseline: 5.2118x; 1.9654x over previous
//
#include <hip/hip_runtime.h>

typedef unsigned int uint;
typedef unsigned short ushort;
typedef unsigned long long ull;
typedef __attribute__((ext_vector_type(8))) short bf16x8;
typedef __attribute__((ext_vector_type(4))) float f32x4;
struct ull2{ ull x, y; };

static constexpr int V_ = 32000, E_ = 256, H_ = 512, B_ = 16, S_ = 512, T_ = 128;
static constexpr int H2_ = 1024, G4_ = 2048, D4_ = 4096, KXI_ = 2304; // 256+1024+1024
static constexpr int DSTEPS = T_ - 1;  // 127
static constexpr int MD = 2048;        // padded rows for preds GEMM (2032 valid)
static constexpr int NWG_DEC = 256;
static constexpr float LOG2E = 1.4426950408889634f;
static constexpr int ASTR = 2312;      // AB padded row stride (ushorts)

#define DEVFN __device__ __forceinline__

DEVFN ushort f2bf(float f){ uint u = __builtin_bit_cast(uint, f); u += 0x7fffu + ((u>>16)&1u); return (ushort)(u>>16); }
DEVFN float bf2f(ushort h){ uint u = ((uint)h)<<16; return __builtin_bit_cast(float, u); }
DEVFN float fsig(float x){ float e = __builtin_amdgcn_exp2f(-LOG2E*x); return __builtin_amdgcn_rcpf(1.f+e); }
DEVFN float ftanh(float x){ x = fminf(15.f,fmaxf(-15.f,x)); float e = __builtin_amdgcn_exp2f(2.f*LOG2E*x); return (e-1.f)*__builtin_amdgcn_rcpf(e+1.f); }
DEVFN f32x4 mfma16(bf16x8 a, bf16x8 b, f32x4 c){ return __builtin_amdgcn_mfma_f32_16x16x32_bf16(a,b,c,0,0,0); }

// ---- coherent (L3-point, sc1) helpers: ONLY for step-communicated buffers ----
DEVFN ull ald64(const void* p){ return __hip_atomic_load((const ull*)p, __ATOMIC_RELAXED, __HIP_MEMORY_SCOPE_AGENT); }
DEVFN uint ald32u(const uint* p){ return __hip_atomic_load(p, __ATOMIC_RELAXED, __HIP_MEMORY_SCOPE_AGENT); }
DEVFN float ald_f32(const float* p){ uint v = __hip_atomic_load((const uint*)p, __ATOMIC_RELAXED, __HIP_MEMORY_SCOPE_AGENT); return __builtin_bit_cast(float, v); }
DEVFN bf16x8 ald_bf16x8(const ushort* p){ ull2 v{ald64(p), ald64(p+4)}; return __builtin_bit_cast(bf16x8, v); }
DEVFN f32x4 ald_f4(const float* p){ ull2 v{ald64(p), ald64(p+2)}; return __builtin_bit_cast(f32x4, v); }
DEVFN void ast32(float* p, float v){ __hip_atomic_store(p, v, __ATOMIC_RELAXED, __HIP_MEMORY_SCOPE_AGENT); }
DEVFN void ast16(ushort* p, ushort v){ __hip_atomic_store(p, v, __ATOMIC_RELAXED, __HIP_MEMORY_SCOPE_AGENT); }
DEVFN uint afadd(uint* p){ return __hip_atomic_fetch_add(p, 1u, __ATOMIC_RELAXED, __HIP_MEMORY_SCOPE_AGENT); }

// fence-free two-level grid barrier (256 WGs = 16 groups x 16), monotonic rounds
DEVFN void dbar(uint* flags, int wgid, int tid, uint& rnd){
  __syncthreads();
  if (tid==0){
    uint* gcnt = flags + (wgid>>4)*16;
    uint* rcnt = flags + 256;
    uint* rgen = flags + 272;
    uint a = afadd(gcnt);
    if (a == rnd*16u+15u){
      uint r = afadd(rcnt);
      if (r == rnd*16u+15u) afadd(rgen);
    }
    while (ald32u(rgen) <= rnd) __builtin_amdgcn_s_sleep(2);
  }
  rnd++;
  __syncthreads();
}

__global__ void k_init(uint* __restrict__ flags, ushort* __restrict__ hgf, ushort* __restrict__ hgb){
  int i = blockIdx.x*256 + threadIdx.x;
  if (i < 512) flags[i] = 0;
  if (i < 2*B_*H_){ hgf[i]=0; hgb[i]=0; }
}

// ---------------- embedding gather ----------------
__global__ void k_embed(const int* __restrict__ src, const int* __restrict__ tgt,
                        const float* __restrict__ emb, ushort* __restrict__ Xb, ushort* __restrict__ DXb){
  int r = blockIdx.x, tid = threadIdx.x;
  if (r < S_*B_){
    int s = r>>4, b = r&15;
    int id = src[b*S_+s];
    Xb[(size_t)r*E_+tid] = f2bf(emb[(size_t)id*E_+tid]);
  } else {
    int r2 = r - S_*B_;
    int t = r2>>4, b = r2&15;
    int id = tgt[b*T_+t];
    DXb[(size_t)r2*E_+tid] = f2bf(emb[(size_t)id*E_+tid]);
  }
}

// encoder Wih convert (gate permuted)
__global__ void k_cvt_encw(const float* __restrict__ src, ushort* __restrict__ dst){
  int d = blockIdx.x;
  int wg = d>>6, r = d&63;
  int w = r>>5, jj=(r>>2)&7, g=r&3;
  int srow = g*H_ + wg*16 + w*8 + jj;
  for (int c = threadIdx.x; c < E_; c += 256)
    dst[(size_t)d*E_ + c] = f2bf(src[(size_t)srow*E_ + c]);
}

__global__ void k_bias_encp(const float* __restrict__ bih, const float* __restrict__ bhh, float* __restrict__ dst){
  int d = blockIdx.x*256 + threadIdx.x;
  int wg = d>>6, r = d&63;
  int w = r>>5, jj=(r>>2)&7, g=r&3;
  int srow = g*H_ + wg*16 + w*8 + jj;
  dst[d] = bih[srow]+bhh[srow];
}

// decoder Wd convert: dst row d: wg=d>>4, r=d&15, jj=r>>2, g=r&3 -> src row g*1024 + wg*4 + jj
__global__ void k_cvt_decw(const float* __restrict__ Wih_d, const float* __restrict__ Whh_d,
                           ushort* __restrict__ dst){
  int d = blockIdx.x;
  int wg = d>>4, r = d&15, jj = r>>2, g = r&3;
  int srow = g*H2_ + wg*4 + jj;
  for (int c = threadIdx.x; c < KXI_; c += 256){
    float v = (c < E_+H2_) ? Wih_d[(size_t)srow*(E_+H2_) + c] : Whh_d[(size_t)srow*H2_ + (c - (E_+H2_))];
    dst[(size_t)d*KXI_ + c] = f2bf(v);
  }
}

__global__ void k_bias_decp(const float* __restrict__ bih, const float* __restrict__ bhh, float* __restrict__ dst){
  int d = blockIdx.x*256 + threadIdx.x;
  int wg = d>>4, r = d&15, jj = r>>2, g = r&3;
  int srow = g*H2_ + wg*4 + jj;
  dst[d] = bih[srow]+bhh[srow];
}

__global__ void k_cvt_strided(const float* __restrict__ src, ushort* __restrict__ dst,
                              int cols, int sld, int soff, int dld, int doff){
  int r = blockIdx.x;
  for (int c = threadIdx.x; c < cols; c += 256)
    dst[(size_t)r*dld + doff + c] = f2bf(src[(size_t)r*sld + soff + c]);
}

__global__ void k_zero_t0(float* __restrict__ out){
  int i = blockIdx.x*256 + threadIdx.x;
  if (i < B_*V_){ int b = i / V_, v = i - b*V_; out[(size_t)b*T_*V_ + v] = 0.f; }
}

// ---------------- 128x128-tile bf16 MFMA GEMM: C[M,N] = A[MxK] @ B[NxK]^T + bias ----------------
// MODE 0 f32 out; MODE 1 bf16 out; MODE 2 scatter preds; MODE 3 bf16 out in [s][col][b] layout
template<int MODE>
__global__ __launch_bounds__(256) void gemm128(const ushort* __restrict__ A, const ushort* __restrict__ Bm,
    const float* __restrict__ bias, void* __restrict__ outp, int M, int N, int K, int Mvalid){
  __shared__ __align__(16) ushort As[128*32];
  __shared__ __align__(16) ushort Bs[128*32];
  int tid = threadIdx.x;
  int wave = tid>>6, lane = tid&63;
  int m0 = blockIdx.y*128, n0 = blockIdx.x*128;
  int wm = wave>>1, wn = wave&1;
  int col = lane&15, rg = lane>>4;
  f32x4 acc[4][4];
  #pragma unroll
  for (int i=0;i<4;i++)
    #pragma unroll
    for (int j=0;j<4;j++) acc[i][j] = {0.f,0.f,0.f,0.f};
  for (int k0=0;k0<K;k0+=32){
    __syncthreads();
    #pragma unroll
    for (int j=0;j<2;j++){
      int li = j*256+tid;
      int row = li>>2, ko = (li&3)*8;
      *(bf16x8*)(As + li*8) = *(const bf16x8*)(A + (size_t)(m0+row)*K + k0 + ko);
      *(bf16x8*)(Bs + li*8) = *(const bf16x8*)(Bm + (size_t)(n0+row)*K + k0 + ko);
    }
    __syncthreads();
    bf16x8 af[4], bfr[4];
    #pragma unroll
    for (int f=0;f<4;f++){
      af[f]  = *(const bf16x8*)(As + (wm*64+f*16+col)*32 + rg*8);
      bfr[f] = *(const bf16x8*)(Bs + (wn*64+f*16+col)*32 + rg*8);
    }
    #pragma unroll
    for (int fm=0;fm<4;fm++)
      #pragma unroll
      for (int fn=0;fn<4;fn++)
        acc[fm][fn] = mfma16(af[fm], bfr[fn], acc[fm][fn]);
  }
  #pragma unroll
  for (int fm=0;fm<4;fm++){
    int mrow = m0 + wm*64 + fm*16 + rg*4;
    #pragma unroll
    for (int fn=0;fn<4;fn++){
      int gcol = n0 + wn*64 + fn*16 + col;
      float bv = bias ? bias[gcol] : 0.f;
      #pragma unroll
      for (int i=0;i<4;i++){
        float v = acc[fm][fn][i] + bv;
        int grow = mrow + i;
        if (MODE==0) ((float*)outp)[(size_t)grow*N + gcol] = v;
        else if (MODE==1) ((ushort*)outp)[(size_t)grow*N + gcol] = f2bf(v);
        else if (MODE==3) ((ushort*)outp)[(size_t)(grow>>4)*(16*2048) + gcol*16 + (grow&15)] = f2bf(v);
        else { if (grow < Mvalid){ int b = grow&15, t = grow>>4;
               ((float*)outp)[(size_t)b*T_*V_ + (size_t)(t+1)*V_ + gcol] = v; } }
      }
    }
  }
}

// ---------------- persistent bidirectional encoder (fence-free barriers) ----------------
__global__ __launch_bounds__(128) void k_enc_persist(
    const ushort* __restrict__ Xgf, const ushort* __restrict__ Xgb,
    const float* __restrict__ Whhf, const float* __restrict__ Whhb,
    ushort* __restrict__ enc, ushort* __restrict__ enct,
    ushort* __restrict__ hbuf1, float* __restrict__ cbuf0,
    ushort* __restrict__ hgf, ushort* __restrict__ hgb,
    uint* __restrict__ flags){
  const int dir = blockIdx.x >> 5;
  const int wg  = blockIdx.x & 31;
  const ushort* Xg = dir ? Xgb : Xgf;
  const float* Whh = dir ? Whhb : Whhf;
  ushort* hg = dir ? hgb : hgf;
  uint* cnt = flags + 288 + dir*32;
  uint* gen = cnt + 16;
  __shared__ __align__(16) ushort Wlds[64*512];   // 64 KiB, XOR-swizzled
  int tid = threadIdx.x;
  for (int r = 0; r < 64; ++r){
    int w_ = r>>5, jj = (r>>2)&7, g = r&3;
    int srow = g*H_ + wg*16 + w_*8 + jj;
    float4 v = *(const float4*)(Whh + (size_t)srow*H_ + tid*4);
    ushort4 o; o.x=f2bf(v.x); o.y=f2bf(v.y); o.z=f2bf(v.z); o.w=f2bf(v.w);
    int byte = (r*1024 + tid*8) ^ ((r&7)<<4);
    *(ushort4*)((char*)Wlds + byte) = o;
  }
  __syncthreads();
  int w = tid>>6, lane = tid&63, colL = lane&15, rg = lane>>4;
  int gg = colL&3;
  uint rnd = 0;
  float cst[8];
  #pragma unroll
  for (int i=0;i<8;i++) cst[i]=0.f;
  for (int t=0;t<S_;++t){
    int pos = dir ? (S_-1-t) : t;
    const ushort* hsrc = hg + (t&1)*B_*H_;
    bf16x8 af[16];
    #pragma unroll
    for (int kt=0;kt<16;kt++)
      af[kt] = ald_bf16x8(hsrc + colL*H_ + rg*8 + kt*32);
    f32x4 acc[2];
    #pragma unroll
    for (int tile=0;tile<2;tile++){
      int colg = wg*64 + w*32 + tile*16 + colL;
      const ushort* xp = Xg + ((size_t)pos*2048 + colg)*16 + rg*4;
      ushort4 xv = *(const ushort4*)xp;
      acc[tile][0] = bf2f(xv.x); acc[tile][1] = bf2f(xv.y);
      acc[tile][2] = bf2f(xv.z); acc[tile][3] = bf2f(xv.w);
    }
    #pragma unroll
    for (int tile=0;tile<2;tile++){
      int rowb = w*32 + tile*16 + colL;
      int base = rowb*1024 + rg*16;
      int xm = (rowb&7)<<4;
      #pragma unroll
      for (int kt=0;kt<16;kt++){
        bf16x8 bfv = *(const bf16x8*)((const char*)Wlds + ((base + kt*64) ^ xm));
        acc[tile] = mfma16(af[kt], bfv, acc[tile]);
      }
    }
    ushort* hdst = hg + ((t+1)&1)*B_*H_;
    #pragma unroll
    for (int tile=0;tile<2;tile++){
      #pragma unroll
      for (int i=0;i<4;i++){
        float v0 = acc[tile][i];
        float v1 = __shfl_xor(v0, 1);
        float v2 = __shfl_xor(v0, 2);
        float v3 = __shfl_xor(v1, 2);
        float zi = gg==0?v0: gg==1?v1: gg==2?v2: v3;
        float zf = (gg^1)==0?v0: (gg^1)==1?v1: (gg^1)==2?v2: v3;
        float zg = (gg^2)==0?v0: (gg^2)==1?v1: (gg^2)==2?v2: v3;
        float zo = (gg^3)==0?v0: (gg^3)==1?v1: (gg^3)==2?v2: v3;
        float cc = fsig(zf)*cst[tile*4+i] + fsig(zi)*ftanh(zg);
        cst[tile*4+i] = cc;
        float h = fsig(zo)*ftanh(cc);
        if (gg==0){
          int j = wg*16 + w*8 + tile*4 + (colL>>2);
          int b = rg*4+i;
          ushort hb = f2bf(h);
          enc[((size_t)b*S_ + pos)*H2_ + dir*H_ + j] = hb;
          enct[((size_t)b*H2_ + dir*H_ + j)*S_ + pos] = hb;
          ast16(&hdst[b*H_ + j], hb);
          if (t==S_-1){
            hbuf1[b*H2_ + dir*H_ + j] = hb;   // decoder h0 (slot 1)
            cbuf0[b*H2_ + dir*H_ + j] = cc;   // decoder c0
          }
        }
      }
    }
    if (t != S_-1){
      __syncthreads();
      if (tid==0){
        uint a = afadd(cnt);
        if (a == rnd*32u+31u) afadd(gen);
        while (ald32u(gen) <= rnd) __builtin_amdgcn_s_sleep(2);
      }
      rnd++;
      __syncthreads();
    }
  }
}

// ---------------- persistent decoder: 256 WGs x 512 threads, fence-free ----------------
__global__ __launch_bounds__(512) void k_dec(
    const float* __restrict__ P, const ushort* __restrict__ WaH,
    const ushort* __restrict__ Wd, const float* __restrict__ bsd,
    const ushort* __restrict__ enct, const ushort* __restrict__ DXb,
    const float* __restrict__ cbuf0, ushort* __restrict__ hbuf,
    ushort* __restrict__ ctxbuf, float* __restrict__ qbuf,
    float* __restrict__ scores, ushort* __restrict__ hsd,
    uint* __restrict__ flags){
  __shared__ __align__(16) ushort AB[16*ASTR];   // 74KB: phase-A h-stage / phase-D xi-stage
  __shared__ __align__(16) float pr[8*256];
  __shared__ float redz[256];
  __shared__ float wls[512];
  __shared__ float part[512];
  __shared__ float red[16];
  __shared__ float cst[64];
  int wgid = blockIdx.x, tid = threadIdx.x;
  int w = tid>>6, lane = tid&63, colL = lane&15, rg = lane>>4;
  uint rnd = 0;
  if (tid < 64){
    int jj = tid>>4, b = tid&15;
    cst[tid] = cbuf0[b*H2_ + wgid*4 + jj];
  }
  for (int st=0; st<DSTEPS; ++st){
    ushort* hprev = hbuf + ((st+1)&1)*B_*H2_;
    // ---- phase A: q = h_{t-1} @ WaH^T  (WGs 0..63, k-split over 8 waves) ----
    if (wgid < 64){
      #pragma unroll
      for (int k2=0;k2<4;k2++){
        int idx = tid + k2*512;          // 2048 ushort8 = 16x1024
        int row = idx>>7, seg = idx&127;
        *(bf16x8*)&AB[row*1032 + seg*8] = ald_bf16x8(hprev + row*H2_ + seg*8);
      }
      __syncthreads();
      int n0 = wgid*16;
      f32x4 acc = {0.f,0.f,0.f,0.f};
      const ushort* Bp = WaH + (size_t)(n0+colL)*H2_ + w*128 + rg*8;
      #pragma unroll
      for (int kt=0;kt<4;kt++){
        bf16x8 afv = *(const bf16x8*)&AB[colL*1032 + w*128 + kt*32 + rg*8];
        acc = mfma16(afv, *(const bf16x8*)(Bp + kt*32), acc);
      }
      *(f32x4*)&pr[w*256 + lane*4] = acc;
      __syncthreads();
      if (tid < 256){
        float s = pr[tid];
        #pragma unroll
        for (int w8=1;w8<8;w8++) s += pr[w8*256 + tid];
        int l = tid>>2, i = tid&3;
        ast32(&qbuf[(size_t)((l>>4)*4 + i)*H2_ + n0 + (l&15)], s);
      }
    }
    dbar(flags, wgid, tid, rnd);
    // ---- phase B: scores[b,s] = sum_k tanh(P + q) (4 rows/wave) ----
    {
      int b = wgid>>4, wc = wgid&15;
      f32x4 qv[4];
      #pragma unroll
      for (int u=0;u<4;u++) qv[u] = ald_f4(qbuf + (size_t)b*H2_ + lane*16 + u*4);
      int rbase = b*S_ + wc*32 + w*4;
      #pragma unroll
      for (int rr=0;rr<4;rr++){
        int r = rbase + rr;
        const float4* Pr = (const float4*)(P + (size_t)r*H2_) + lane*4;
        float s = 0.f;
        #pragma unroll
        for (int u=0;u<4;u++){
          float4 pv = Pr[u];
          s += ftanh(pv.x+qv[u][0])+ftanh(pv.y+qv[u][1])+ftanh(pv.z+qv[u][2])+ftanh(pv.w+qv[u][3]);
        }
        #pragma unroll
        for (int o=32;o;o>>=1) s += __shfl_xor(s,o);
        if (lane==0) ast32(&scores[r], s);
      }
    }
    dbar(flags, wgid, tid, rnd);
    // ---- phase C: softmax (replicated per b) + ctx via ENCT ----
    {
      int b = wgid>>4, cc = wgid&15;
      float sc = ald_f32(scores + b*S_ + tid);
      float m = sc;
      #pragma unroll
      for (int o=32;o;o>>=1) m = fmaxf(m, __shfl_xor(m,o));
      if (lane==0) red[w] = m;
      __syncthreads();
      m = red[0];
      #pragma unroll
      for (int k2=1;k2<8;k2++) m = fmaxf(m, red[k2]);
      float e = __builtin_amdgcn_exp2f((sc - m)*LOG2E);
      float ss = e;
      #pragma unroll
      for (int o=32;o;o>>=1) ss += __shfl_xor(ss,o);
      if (lane==0) red[8+w] = ss;
      __syncthreads();
      float tot = red[8];
      #pragma unroll
      for (int k2=9;k2<16;k2++) tot += red[k2];
      wls[tid] = e * __builtin_amdgcn_rcpf(tot);
      __syncthreads();
      int c = cc*64 + (tid&63), sseg = tid>>6;
      const ushort* ep = enct + ((size_t)b*H2_ + c)*S_ + sseg*64;
      float a = 0.f;
      #pragma unroll
      for (int u=0;u<8;u++){
        bf16x8 ev = *(const bf16x8*)(ep + u*8);
        #pragma unroll
        for (int j=0;j<8;j++) a += wls[sseg*64 + u*8 + j] * bf2f((ushort)ev[j]);
      }
      part[tid] = a;
      __syncthreads();
      if (tid < 64){
        float s = part[tid];
        #pragma unroll
        for (int g2=1;g2<8;g2++) s += part[g2*64 + tid];
        ast16(&ctxbuf[b*H2_ + cc*64 + tid], f2bf(s));
      }
    }
    dbar(flags, wgid, tid, rnd);
    // ---- phase D: gates = [x|ctx|h] @ Wd^T + cell (16 rows/WG, k-split 8x288) ----
    {
      { int b3 = tid>>5, seg = tid&31;
        *(bf16x8*)&AB[b3*ASTR + seg*8] = *(const bf16x8*)(DXb + ((size_t)(st*16+b3))*E_ + seg*8); }
      #pragma unroll
      for (int k2=0;k2<4;k2++){
        int idx = tid + k2*512;
        int row = idx>>7, seg = idx&127;
        *(bf16x8*)&AB[row*ASTR + 256 + seg*8]  = ald_bf16x8(ctxbuf + row*H2_ + seg*8);
        *(bf16x8*)&AB[row*ASTR + 1280 + seg*8] = ald_bf16x8(hprev + row*H2_ + seg*8);
      }
      __syncthreads();
      int row0 = wgid*16;
      f32x4 acc = {0.f,0.f,0.f,0.f};
      const ushort* Bp = Wd + (size_t)(row0+colL)*KXI_ + w*288 + rg*8;
      #pragma unroll
      for (int kt=0;kt<9;kt++){
        bf16x8 afv = *(const bf16x8*)&AB[colL*ASTR + w*288 + kt*32 + rg*8];
        acc = mfma16(afv, *(const bf16x8*)(Bp + kt*32), acc);
      }
      *(f32x4*)&pr[w*256 + lane*4] = acc;
      __syncthreads();
      if (tid < 256){
        float s = bsd[row0 + ((tid>>2)&15)];
        #pragma unroll
        for (int w8=0;w8<8;w8++) s += pr[w8*256 + tid];
        redz[tid] = s;
      }
      __syncthreads();
      if (tid < 64){
        int jj = tid>>4, b4 = tid&15, rgc = b4>>2, ic = b4&3;
        float zi = redz[((jj*4+0) + 16*rgc)*4 + ic];
        float zf = redz[((jj*4+1) + 16*rgc)*4 + ic];
        float zg = redz[((jj*4+2) + 16*rgc)*4 + ic];
        float zo = redz[((jj*4+3) + 16*rgc)*4 + ic];
        float cc2 = fsig(zf)*cst[tid] + fsig(zi)*ftanh(zg);
        cst[tid] = cc2;
        float h = fsig(zo)*ftanh(cc2);
        ushort hb = f2bf(h);
        int j = wgid*4 + jj;
        ast16(&(hbuf + (st&1)*B_*H2_)[b4*H2_ + j], hb);
        hsd[((size_t)st*B_ + b4)*H2_ + j] = hb;
      }
      __syncthreads();
    }
    if (st != DSTEPS-1) dbar(flags, wgid, tid, rnd);
  }
}

extern "C" void kernel_launch(void* const* d_in, const int* in_sizes, int n_in,
                              void* d_out, int out_size, void* d_ws, size_t ws_size,
                              hipStream_t stream) {
  const int* src   = (const int*)d_in[0];
  const int* tgt   = (const int*)d_in[1];
  const float* emb   = (const float*)d_in[2];
  const float* Wih_f = (const float*)d_in[3];
  const float* Whh_f = (const float*)d_in[4];
  const float* bih_f = (const float*)d_in[5];
  const float* bhh_f = (const float*)d_in[6];
  const float* Wih_b = (const float*)d_in[7];
  const float* Whh_b = (const float*)d_in[8];
  const float* bih_b = (const float*)d_in[9];
  const float* bhh_b = (const float*)d_in[10];
  const float* Wih_d = (const float*)d_in[11];
  const float* Whh_d = (const float*)d_in[12];
  const float* bih_d = (const float*)d_in[13];
  const float* bhh_d = (const float*)d_in[14];
  const float* Wa    = (const float*)d_in[15];
  const float* ba    = (const float*)d_in[16];
  const float* Wo    = (const float*)d_in[17];
  const float* bo    = (const float*)d_in[18];
  float* out = (float*)d_out;
  (void)in_sizes; (void)n_in; (void)out_size; (void)ws_size;

  char* ws = (char*)d_ws;
  size_t off = 0;
  auto alloc = [&](size_t bytes)->char*{ char* p = ws + off; off += (bytes + 255) & ~(size_t)255; return p; };
  ushort* Xb     = (ushort*)alloc((size_t)S_*B_*E_*2);
  ushort* DXb    = (ushort*)alloc((size_t)DSTEPS*B_*E_*2);
  ushort* Wihf_p = (ushort*)alloc((size_t)G4_*E_*2);
  ushort* Wihb_p = (ushort*)alloc((size_t)G4_*E_*2);
  float*  bsf    = (float*)alloc(G4_*4);
  float*  bsb    = (float*)alloc(G4_*4);
  ushort* ENC    = (ushort*)alloc((size_t)B_*S_*H2_*2);
  ushort* ENCT   = (ushort*)alloc((size_t)B_*S_*H2_*2);
  ushort* WaH    = (ushort*)alloc((size_t)H2_*H2_*2);
  ushort* WaE    = (ushort*)alloc((size_t)H2_*H2_*2);
  ushort* Wd     = (ushort*)alloc((size_t)D4_*KXI_*2);
  float*  bsd    = (float*)alloc(D4_*4);
  ushort* WoB    = (ushort*)alloc((size_t)V_*H2_*2);
  float*  cbuf0  = (float*)alloc(B_*H2_*4);
  ushort* hbuf   = (ushort*)alloc((size_t)2*B_*H2_*2);
  ushort* ctxbuf = (ushort*)alloc((size_t)B_*H2_*2);
  float*  qbuf   = (float*)alloc(B_*H2_*4);
  float*  scores = (float*)alloc(B_*S_*4);
  ushort* hsd    = (ushort*)alloc((size_t)MD*H2_*2);
  ushort* hgf    = (ushort*)alloc((size_t)2*B_*H_*2);
  ushort* hgb    = (ushort*)alloc((size_t)2*B_*H_*2);
  uint*   flags  = (uint*)alloc(2048);
  char*   big    = alloc((size_t)2*S_*B_*G4_*2);   // Xgf+Xgb; later aliased by P (f32)
  ushort* Xgf = (ushort*)big;
  ushort* Xgb = (ushort*)(big + (size_t)S_*B_*G4_*2);
  float*  P   = (float*)big;

  // ---- setup ----
  k_init<<<dim3(64), dim3(256), 0, stream>>>(flags, hgf, hgb);
  k_embed<<<dim3(S_*B_ + DSTEPS*B_), dim3(E_), 0, stream>>>(src, tgt, emb, Xb, DXb);
  k_cvt_encw<<<dim3(G4_), dim3(256), 0, stream>>>(Wih_f, Wihf_p);
  k_cvt_encw<<<dim3(G4_), dim3(256), 0, stream>>>(Wih_b, Wihb_p);
  k_bias_encp<<<dim3(8), dim3(256), 0, stream>>>(bih_f, bhh_f, bsf);
  k_bias_encp<<<dim3(8), dim3(256), 0, stream>>>(bih_b, bhh_b, bsb);
  k_cvt_strided<<<dim3(H2_), dim3(256), 0, stream>>>(Wa, WaH, H2_, 2*H2_, 0,   H2_, 0);
  k_cvt_strided<<<dim3(H2_), dim3(256), 0, stream>>>(Wa, WaE, H2_, 2*H2_, H2_, H2_, 0);
  k_cvt_decw<<<dim3(D4_), dim3(256), 0, stream>>>(Wih_d, Whh_d, Wd);
  k_bias_decp<<<dim3(16), dim3(256), 0, stream>>>(bih_d, bhh_d, bsd);
  k_cvt_strided<<<dim3(V_),  dim3(256), 0, stream>>>(Wo, WoB, H2_, H2_, 0, H2_, 0);

  // ---- encoder input-gate pre-GEMMs -> [s][col][b] layout (MODE 3) ----
  gemm128<3><<<dim3(G4_/128, (S_*B_)/128), dim3(256), 0, stream>>>(Xb, Wihf_p, bsf, Xgf, S_*B_, G4_, E_, 0);
  gemm128<3><<<dim3(G4_/128, (S_*B_)/128), dim3(256), 0, stream>>>(Xb, Wihb_p, bsb, Xgb, S_*B_, G4_, E_, 0);

  // ---- persistent bidirectional encoder (64 WGs) ----
  k_enc_persist<<<dim3(64), dim3(128), 0, stream>>>(Xgf, Xgb, Whh_f, Whh_b, ENC, ENCT,
                                                    hbuf + B_*H2_, cbuf0, hgf, hgb, flags);

  // ---- enc_proj = enc_out @ Wa_e^T + ba ----
  gemm128<0><<<dim3(H2_/128, (B_*S_)/128), dim3(256), 0, stream>>>(ENC, WaE, ba, P, B_*S_, H2_, H2_, 0);
  k_zero_t0<<<dim3((B_*V_+255)/256), dim3(256), 0, stream>>>(out);

  // ---- persistent decoder (256 WGs x 512 threads) ----
  k_dec<<<dim3(NWG_DEC), dim3(512), 0, stream>>>(P, WaH, Wd, bsd, ENCT, DXb, cbuf0, hbuf,
                                                 ctxbuf, qbuf, scores, hsd, flags);

  // ---- final projection ----
  gemm128<2><<<dim3(V_/128, MD/128), dim3(256), 0, stream>>>(hsd, WoB, bo, out, MD, V_, H2_, DSTEPS*B_);
}